// Round 5
// baseline (2676.840 us; speedup 1.0000x reference)
//
#include <hip/hip_runtime.h>
#include <hip/hip_fp16.h>
#include <math.h>
#include <type_traits>

#define NPTS 16384
#define NB 16
#define BNTOT (NB * NPTS)
#define NP 16

struct alignas(8) H4 { __half2 a, b; };

// ---------------------------------------------------------------------------
// Fused 1x1-conv (GEMM) kernel. Each thread: PT=4 points x OT out-channels.
//   MODE 0: X read raw (float or half)
//   MODE 1: X read as relu(insc*x + insh)  (producer BN+ReLU fused on load)
//   MODE 2: concat: c<32 -> vglob[b*32+c]; c>=32 -> raw X (64 phys channels)
// OUTAFF: epilogue v = relu(outsc*v + outsh)  (this layer's BN known upfront)
// TANH_OUT: epilogue v = tanh(v + bias)
// STATS: per-out-channel sum/sumsq of the STORED (raw) output via atomics
// Grid: (COUT/OT, points/1024). Block 256.
// ---------------------------------------------------------------------------
template<int CIN, int OT, int MODE, bool TANH_OUT, bool STATS, bool OUTAFF,
         typename TIN, typename TOUT>
__global__ __launch_bounds__(256, 2) void conv_k(
    const TIN* __restrict__ X, const float* __restrict__ vglob,
    const float* __restrict__ W, const float* __restrict__ bias,
    const float* __restrict__ insc, const float* __restrict__ insh,
    const float* __restrict__ outsc, const float* __restrict__ outsh,
    TOUT* __restrict__ Y, float* __restrict__ ssum, float* __restrict__ ssq,
    int COUT)
{
    constexpr int PT = 4;
    constexpr int NT = 256 * PT;               // 1024 points per block
    constexpr int CC = (CIN < 128) ? CIN : 128;
    constexpr int XC = (MODE == 2) ? 64 : CIN; // physical channels of X
    __shared__ __align__(16) float Ws[CC][OT];
    __shared__ float lsum[OT];
    __shared__ float lsq[OT];

    const int tid = threadIdx.x;
    const int tile = blockIdx.y;
    const int b = (tile * NT) / NPTS;          // local batch (pointers pre-offset)
    const int n = (tile * NT) % NPTS + tid * PT;
    const int obase = blockIdx.x * OT;

    if (STATS) {
        for (int i = tid; i < OT; i += 256) { lsum[i] = 0.f; lsq[i] = 0.f; }
    }

    float acc[OT][PT];
#pragma unroll
    for (int o = 0; o < OT; ++o)
#pragma unroll
        for (int p = 0; p < PT; ++p) acc[o][p] = 0.f;

    const TIN* Xb = X + (size_t)b * XC * NPTS;

    for (int c0 = 0; c0 < CIN; c0 += CC) {
        for (int i = tid; i < CC * OT; i += 256) {
            int c = i % CC, o = i / CC;
            int oo = obase + o;
            Ws[c][o] = (oo < COUT) ? W[(size_t)oo * CIN + (c0 + c)] : 0.f;
        }
        __syncthreads();
#pragma unroll 2
        for (int c = 0; c < CC; ++c) {
            float xv[PT];
            if (MODE == 2 && (c0 + c) < 32) {
                float gv = vglob[b * 32 + (c0 + c)];
#pragma unroll
                for (int p = 0; p < PT; ++p) xv[p] = gv;
            } else {
                const int cx = (MODE == 2) ? (c0 + c - 32) : (c0 + c);
                if constexpr (std::is_same<TIN, __half>::value) {
                    H4 t = *(const H4*)(Xb + (size_t)cx * NPTS + n);
                    xv[0] = __low2float(t.a); xv[1] = __high2float(t.a);
                    xv[2] = __low2float(t.b); xv[3] = __high2float(t.b);
                } else {
                    float4 t = *(const float4*)(Xb + (size_t)cx * NPTS + n);
                    xv[0] = t.x; xv[1] = t.y; xv[2] = t.z; xv[3] = t.w;
                }
                if (MODE == 1) {
                    float s = insc[cx], h = insh[cx];
#pragma unroll
                    for (int p = 0; p < PT; ++p)
                        xv[p] = fmaxf(fmaf(xv[p], s, h), 0.f);
                }
            }
            const float4* wrow = (const float4*)(&Ws[c][0]); // broadcast reads
#pragma unroll
            for (int o4 = 0; o4 < OT / 4; ++o4) {
                float4 w = wrow[o4];
#pragma unroll
                for (int p = 0; p < PT; ++p) {
                    acc[o4 * 4 + 0][p] = fmaf(w.x, xv[p], acc[o4 * 4 + 0][p]);
                    acc[o4 * 4 + 1][p] = fmaf(w.y, xv[p], acc[o4 * 4 + 1][p]);
                    acc[o4 * 4 + 2][p] = fmaf(w.z, xv[p], acc[o4 * 4 + 2][p]);
                    acc[o4 * 4 + 3][p] = fmaf(w.w, xv[p], acc[o4 * 4 + 3][p]);
                }
            }
        }
        __syncthreads();
    }

#pragma unroll
    for (int o = 0; o < OT; ++o) {
        const int oo = obase + o;
        if (oo < COUT) {
            float v[PT];
#pragma unroll
            for (int p = 0; p < PT; ++p) v[p] = acc[o][p];
            if (OUTAFF) {
                float s = outsc[oo], h = outsh[oo];
#pragma unroll
                for (int p = 0; p < PT; ++p) v[p] = fmaxf(fmaf(v[p], s, h), 0.f);
            }
            if (TANH_OUT) {
                float bb = bias[oo];
#pragma unroll
                for (int p = 0; p < PT; ++p) v[p] = tanhf(v[p] + bb);
            }
            const size_t ofs = ((size_t)b * COUT + oo) * NPTS + n;
            if constexpr (std::is_same<TOUT, __half>::value) {
                H4 t; t.a = __floats2half2_rn(v[0], v[1]);
                t.b = __floats2half2_rn(v[2], v[3]);
                *(H4*)(Y + ofs) = t;
            } else {
                *(float4*)(Y + ofs) = make_float4(v[0], v[1], v[2], v[3]);
            }
            if (STATS) {
                float s = v[0] + v[1] + v[2] + v[3];
                float q = fmaf(v[0], v[0], fmaf(v[1], v[1], fmaf(v[2], v[2], v[3] * v[3])));
#pragma unroll
                for (int d = 32; d >= 1; d >>= 1) {
                    s += __shfl_xor(s, d, 64);
                    q += __shfl_xor(q, d, 64);
                }
                if ((tid & 63) == 0) {
                    atomicAdd(&lsum[o], s);
                    atomicAdd(&lsq[o], q);
                }
            }
        }
    }
    if (STATS) {
        __syncthreads();
        for (int i = tid; i < OT; i += 256) {
            int oo = obase + i;
            if (oo < COUT) {
                atomicAdd(&ssum[oo], lsum[i]);
                atomicAdd(&ssq[oo], lsq[i]);
            }
        }
    }
}

// per-channel BN fold: scale = g/sqrt(var+eps), shift = be - mean*scale
__global__ void bnstats_k(const float* __restrict__ ssum, const float* __restrict__ ssq,
                          const float* __restrict__ g, const float* __restrict__ be,
                          float* __restrict__ scale, float* __restrict__ shift, int C)
{
    int c = blockIdx.x * blockDim.x + threadIdx.x;
    if (c >= C) return;
    const float inv = 1.0f / (float)BNTOT;
    float m = ssum[c] * inv;
    float var = fmaf(ssq[c], inv, -m * m);
    float sc = g[c] / sqrtf(var + 1e-5f);
    scale[c] = sc;
    shift[c] = fmaf(-m, sc, be[c]);
}

// SoftPool: per (b,k) select 16 smallest of h3[b,k,:] (stable), then
// v[b,k] = sum_{c,p} w9[c,p] * h3[b,c,idx[p]] + b9.
__global__ __launch_bounds__(256) void softpool_k(
    const float* __restrict__ y3, const float* __restrict__ sc3,
    const float* __restrict__ sh3, const float* __restrict__ w9,
    const float* __restrict__ b9, float* __restrict__ vout)
{
    extern __shared__ float vals[];
    __shared__ int sidx[NP];
    __shared__ float wv[4];
    __shared__ int wi[4];
    __shared__ float ps[4];

    const int tid = threadIdx.x;
    const int b = blockIdx.x >> 5;
    const int k = blockIdx.x & 31;

    const float* src = y3 + ((size_t)b * 32 + k) * NPTS;
    const float sck = sc3[k], shk = sh3[k];
    for (int i = tid; i < NPTS; i += 256) vals[i] = fmaf(src[i], sck, shk);
    __syncthreads();

    for (int p = 0; p < NP; ++p) {
        float bv = INFINITY;
        int bi = 0x7fffffff;
        for (int i = tid; i < NPTS; i += 256) {
            float x = vals[i];
            if (x < bv) { bv = x; bi = i; }
        }
#pragma unroll
        for (int d = 32; d >= 1; d >>= 1) {
            float ov = __shfl_xor(bv, d, 64);
            int oi = __shfl_xor(bi, d, 64);
            if (ov < bv || (ov == bv && oi < bi)) { bv = ov; bi = oi; }
        }
        if ((tid & 63) == 0) { wv[tid >> 6] = bv; wi[tid >> 6] = bi; }
        __syncthreads();
        if (tid == 0) {
            for (int w = 1; w < 4; ++w)
                if (wv[w] < bv || (wv[w] == bv && wi[w] < bi)) { bv = wv[w]; bi = wi[w]; }
            sidx[p] = bi;
            vals[bi] = INFINITY;
        }
        __syncthreads();
    }

    float part = 0.f;
    for (int i = tid; i < 32 * NP; i += 256) {
        int c = i >> 4, p = i & 15;
        float h = fmaf(y3[((size_t)b * 32 + c) * NPTS + sidx[p]], sc3[c], sh3[c]);
        part += w9[c * NP + p] * h;
    }
#pragma unroll
    for (int d = 32; d >= 1; d >>= 1) part += __shfl_xor(part, d, 64);
    if ((tid & 63) == 0) ps[tid >> 6] = part;
    __syncthreads();
    if (tid == 0) vout[b * 32 + k] = ps[0] + ps[1] + ps[2] + ps[3] + b9[0];
}

// h1 = relu(sc1*y1 + sh1) stored fp16; also per-(b,c) sums S1b of the stored values.
__global__ __launch_bounds__(256) void transform_k(
    const float* __restrict__ y1, const float* __restrict__ sc,
    const float* __restrict__ sh, __half* __restrict__ h1, float* __restrict__ S1b)
{
    __shared__ float wsum[4];
    const int tid = threadIdx.x;
    const int b = blockIdx.x >> 6, c = blockIdx.x & 63;
    const float* src = y1 + (size_t)(b * 64 + c) * NPTS;
    __half* dst = h1 + (size_t)(b * 64 + c) * NPTS;
    const float s = sc[c], h = sh[c];
    float acc = 0.f;
    for (int i = tid * 4; i < NPTS; i += 1024) {
        float4 v = *(const float4*)(src + i);
        float r0 = fmaxf(fmaf(v.x, s, h), 0.f);
        float r1 = fmaxf(fmaf(v.y, s, h), 0.f);
        float r2 = fmaxf(fmaf(v.z, s, h), 0.f);
        float r3 = fmaxf(fmaf(v.w, s, h), 0.f);
        H4 o; o.a = __floats2half2_rn(r0, r1); o.b = __floats2half2_rn(r2, r3);
        *(H4*)(dst + i) = o;
        acc += __low2float(o.a) + __high2float(o.a) + __low2float(o.b) + __high2float(o.b);
    }
#pragma unroll
    for (int d = 32; d >= 1; d >>= 1) acc += __shfl_xor(acc, d, 64);
    if ((tid & 63) == 0) wsum[tid >> 6] = acc;
    __syncthreads();
    if (tid == 0) S1b[b * 64 + c] = wsum[0] + wsum[1] + wsum[2] + wsum[3];
}

// M[i][j] = sum over all (b,n) of h1[b,i,n]*h1[b,j,n]  (64x64 SYRK, fp32 accum)
__global__ __launch_bounds__(256) void syrk_k(const __half* __restrict__ h1,
                                              float* __restrict__ M)
{
    __shared__ float hs[64][130];
    const int tid = threadIdx.x;
    const int b = blockIdx.x >> 3;
    const int n0 = (blockIdx.x & 7) * 2048;
    const int i0 = (tid >> 4) * 4, j0 = (tid & 15) * 4;
    float acc[4][4] = {};
    const __half* hb = h1 + (size_t)b * 64 * NPTS;
    for (int s = 0; s < 16; ++s) {
        __syncthreads();
        for (int k = tid; k < 4096; k += 256) {
            int c = k >> 6, p2 = (k & 63) << 1;
            __half2 v = *(const __half2*)(hb + (size_t)c * NPTS + n0 + s * 128 + p2);
            hs[c][p2] = __low2float(v);
            hs[c][p2 + 1] = __high2float(v);
        }
        __syncthreads();
        for (int p = 0; p < 128; ++p) {
            float xi[4], xj[4];
#pragma unroll
            for (int ii = 0; ii < 4; ++ii) xi[ii] = hs[i0 + ii][p];
#pragma unroll
            for (int jj = 0; jj < 4; ++jj) xj[jj] = hs[j0 + jj][p];
#pragma unroll
            for (int ii = 0; ii < 4; ++ii)
#pragma unroll
                for (int jj = 0; jj < 4; ++jj)
                    acc[ii][jj] = fmaf(xi[ii], xj[jj], acc[ii][jj]);
        }
    }
#pragma unroll
    for (int ii = 0; ii < 4; ++ii)
#pragma unroll
        for (int jj = 0; jj < 4; ++jj)
            atomicAdd(&M[(i0 + ii) * 64 + (j0 + jj)], acc[ii][jj]);
}

// BN4 stats from input moments: y4 = W4 . [glob(32); h1(64)], per o:
//   sum  = sum_b (N*g_ob + W4h.S1b[b]),  g_ob = W4g.vv[b]
//   sumsq= sum_b (N*g_ob^2 + 2*g_ob*(W4h.S1b[b])) + W4h^T M W4h
__global__ void bnstats45_k(const float* __restrict__ w4, const float* __restrict__ vv,
                            const float* __restrict__ S1b, const float* __restrict__ M,
                            const float* __restrict__ g, const float* __restrict__ be,
                            float* __restrict__ sc4, float* __restrict__ sh4)
{
    __shared__ float vvL[512], sbL[1024], ML[4096];
    const int tid = threadIdx.x;
    for (int i = tid; i < 512; i += 512) vvL[i] = vv[i];
    for (int i = tid; i < 1024; i += 512) sbL[i] = S1b[i];
    for (int i = tid; i < 4096; i += 512) ML[i] = M[i];
    __syncthreads();
    const int o = tid;
    float wg[32], wh[64];
#pragma unroll
    for (int i = 0; i < 32; ++i) wg[i] = w4[o * 96 + i];
#pragma unroll
    for (int j = 0; j < 64; ++j) wh[j] = w4[o * 96 + 32 + j];
    float sumy = 0.f, sumsq = 0.f;
    for (int b = 0; b < 16; ++b) {
        float gb = 0.f, hb = 0.f;
#pragma unroll
        for (int i = 0; i < 32; ++i) gb = fmaf(wg[i], vvL[b * 32 + i], gb);
#pragma unroll
        for (int j = 0; j < 64; ++j) hb = fmaf(wh[j], sbL[b * 64 + j], hb);
        sumy += (float)NPTS * gb + hb;
        sumsq += (float)NPTS * gb * gb + 2.f * gb * hb;
    }
    for (int j = 0; j < 64; ++j) {
        float t = 0.f;
#pragma unroll
        for (int j2 = 0; j2 < 64; ++j2) t = fmaf(ML[j * 64 + j2], wh[j2], t);
        sumsq = fmaf(wh[j], t, sumsq);
    }
    const float inv = 1.0f / (float)BNTOT;
    float m = sumy * inv;
    float var = fmaf(sumsq, inv, -m * m);
    float s = g[o] / sqrtf(var + 1e-5f);
    sc4[o] = s;
    sh4[o] = fmaf(-m, s, be[o]);
}

// Diagnostic fallback (kept): encodes ws_size (MB) into out if ws too small.
__global__ void fill_k(float* __restrict__ out, int nsize, float val)
{
    int i = blockIdx.x * 256 + threadIdx.x;
    if (i < nsize) out[i] = val;
}

extern "C" void kernel_launch(void* const* d_in, const int* in_sizes, int n_in,
                              void* d_out, int out_size, void* d_ws, size_t ws_size,
                              hipStream_t stream)
{
    const float* x   = (const float*)d_in[0];
    const float* w1  = (const float*)d_in[1];
    const float* g1  = (const float*)d_in[3];
    const float* be1 = (const float*)d_in[4];
    const float* w2  = (const float*)d_in[5];
    const float* g2  = (const float*)d_in[7];
    const float* be2 = (const float*)d_in[8];
    const float* w3  = (const float*)d_in[9];
    const float* g3  = (const float*)d_in[11];
    const float* be3 = (const float*)d_in[12];
    const float* w9  = (const float*)d_in[13];
    const float* b9  = (const float*)d_in[14];
    const float* w4  = (const float*)d_in[15];
    const float* g4  = (const float*)d_in[17];
    const float* be4 = (const float*)d_in[18];
    const float* w5  = (const float*)d_in[19];
    const float* g5  = (const float*)d_in[21];
    const float* be5 = (const float*)d_in[22];
    const float* w6  = (const float*)d_in[23];
    const float* g6  = (const float*)d_in[25];
    const float* be6 = (const float*)d_in[26];
    const float* w7  = (const float*)d_in[27];
    const float* b7  = (const float*)d_in[28];
    float* out = (float*)d_out;

    // ---- workspace plan (256 MiB), lifetime-aliased ----
    //   [0,64M):    y1 fp32 (conv1..transform) -> h4buf fp16 (conv45 loop) -> y6 fp16
    //   [64M,192M): y2 fp32 (conv2..conv3); after softpool: h1 fp16 [64M,96M)
    //   [96M,224M): y5 fp16 (conv5..conv6)
    //   [192M,224M):y3 fp32 (conv3..softpool)  (dead before y5 tail written)
    //   [224M,..):  stats block (67584 B)
    const size_t MB = 1048576u;
    const size_t STATS_OFF = 224 * MB;
    const size_t need = STATS_OFF + 67584u;
    if (ws_size < need) {
        float val = 1000.0f + (float)(ws_size >> 20);
        fill_k<<<(out_size + 255) / 256, 256, 0, stream>>>(out, out_size, val);
        return;
    }

    char* base = (char*)d_ws;
    float*  y1    = (float*)base;
    __half* h4buf = (__half*)base;
    __half* y6    = (__half*)base;
    float*  y2    = (float*)(base + 64 * MB);
    __half* h1    = (__half*)(base + 64 * MB);
    __half* y5    = (__half*)(base + 96 * MB);
    float*  y3    = (float*)(base + 192 * MB);
    float*  sm    = (float*)(base + STATS_OFF);

    float* sum1 = sm + 0,     *sq1 = sm + 512,  *sc1 = sm + 1024, *sh1 = sm + 1536;
    float* sum2 = sm + 2048,  *sq2 = sm + 2560, *sc2 = sm + 3072, *sh2 = sm + 3584;
    float* sum3 = sm + 4096,  *sq3 = sm + 4608, *sc3 = sm + 5120, *sh3 = sm + 5632;
    float* sc4  = sm + 6144,  *sh4 = sm + 6656;
    float* sum5 = sm + 7168,  *sq5 = sm + 7680, *sc5 = sm + 8192, *sh5 = sm + 8704;
    float* sum6 = sm + 9216,  *sq6 = sm + 9728, *sc6 = sm + 10240,*sh6 = sm + 10752;
    float* vv   = sm + 11264;            // 512
    float* S1b  = sm + 11776;            // 1024
    float* Mh   = sm + 12800;            // 4096; end = 16896 floats

    hipMemsetAsync(sm, 0, 16896 * sizeof(float), stream);

    const dim3 blk(256);
    const int tilesF = BNTOT / 1024;     // 256 (full tensors)
    const int tilesQ = (4 * NPTS) / 1024; // 64 (4-batch chunk)

    // conv1: 4 -> 64, fp32
    conv_k<4, 32, 0, false, true, false, float, float>
        <<<dim3(2, tilesF), blk, 0, stream>>>(x, nullptr, w1, nullptr, nullptr, nullptr,
            nullptr, nullptr, y1, sum1, sq1, 64);
    bnstats_k<<<1, 256, 0, stream>>>(sum1, sq1, g1, be1, sc1, sh1, 64);

    // conv2: 64 -> 128, fp32
    conv_k<64, 32, 1, false, true, false, float, float>
        <<<dim3(4, tilesF), blk, 0, stream>>>(y1, nullptr, w2, nullptr, sc1, sh1,
            nullptr, nullptr, y2, sum2, sq2, 128);
    bnstats_k<<<1, 256, 0, stream>>>(sum2, sq2, g2, be2, sc2, sh2, 128);

    // conv3: 128 -> 32, fp32
    conv_k<128, 32, 1, false, true, false, float, float>
        <<<dim3(1, tilesF), blk, 0, stream>>>(y2, nullptr, w3, nullptr, sc2, sh2,
            nullptr, nullptr, y3, sum3, sq3, 32);
    bnstats_k<<<1, 256, 0, stream>>>(sum3, sq3, g3, be3, sc3, sh3, 32);

    // softpool -> vv[16*32]
    softpool_k<<<512, blk, NPTS * sizeof(float), stream>>>(y3, sc3, sh3, w9, b9, vv);

    // h1 = relu(bn1(y1)) fp16 + per-(b,c) sums; then 64x64 moment; then BN4 stats
    transform_k<<<1024, blk, 0, stream>>>(y1, sc1, sh1, h1, S1b);
    syrk_k<<<128, blk, 0, stream>>>(h1, Mh);
    bnstats45_k<<<1, 512, 0, stream>>>(w4, vv, S1b, Mh, g4, be4, sc4, sh4);

    // conv4+conv5 in 4 batch-chunks (4 batches each); h4 bounce buffer 64MB fp16
    for (int q = 0; q < 4; ++q) {
        const __half* h1q = h1 + (size_t)q * 4 * 64 * NPTS;
        const float*  vvq = vv + q * 4 * 32;
        __half* y5q = y5 + (size_t)q * 4 * 256 * NPTS;
        // conv4: concat(glob32, h1) -> 512, epilogue BN4+ReLU, fp16 out
        conv_k<96, 32, 2, false, false, true, __half, __half>
            <<<dim3(16, tilesQ), blk, 0, stream>>>(h1q, vvq, w4, nullptr, nullptr, nullptr,
                sc4, sh4, h4buf, nullptr, nullptr, 512);
        // conv5: 512 -> 256, raw fp16 out + stats
        conv_k<512, 32, 0, false, true, false, __half, __half>
            <<<dim3(8, tilesQ), blk, 0, stream>>>(h4buf, nullptr, w5, nullptr, nullptr, nullptr,
                nullptr, nullptr, y5q, sum5, sq5, 256);
    }
    bnstats_k<<<1, 256, 0, stream>>>(sum5, sq5, g5, be5, sc5, sh5, 256);

    // conv6: 256 -> 128, fp16
    conv_k<256, 32, 1, false, true, false, __half, __half>
        <<<dim3(4, tilesF), blk, 0, stream>>>(y5, nullptr, w6, nullptr, sc5, sh5,
            nullptr, nullptr, y6, sum6, sq6, 128);
    bnstats_k<<<1, 256, 0, stream>>>(sum6, sq6, g6, be6, sc6, sh6, 128);

    // conv7: 128 -> 3, +bias, tanh, fp32 out
    conv_k<128, 4, 1, true, false, false, __half, float>
        <<<dim3(1, tilesF), blk, 0, stream>>>(y6, nullptr, w7, b7, sc6, sh6,
            nullptr, nullptr, out, nullptr, nullptr, 3);
}

// Round 6
// 1705.226 us; speedup vs baseline: 1.5698x; 1.5698x over previous
//
#include <hip/hip_runtime.h>
#include <hip/hip_fp16.h>
#include <math.h>
#include <type_traits>

#define NPTS 16384
#define NB 16
#define BNTOT (NB * NPTS)
#define NP 16

typedef _Float16 f16;
typedef __attribute__((ext_vector_type(8))) _Float16 f16x8;
typedef __attribute__((ext_vector_type(4))) float f32x4;

struct alignas(8) H4 { __half2 a, b; };
struct alignas(8) F16x4 { f16 v[4]; };

// ---------------------------------------------------------------------------
// Legacy fp32 VALU conv (UNCHANGED from passing round — conv1..conv3 must stay
// bit-identical: SoftPool's argsort selection is chaotic under reordering).
// ---------------------------------------------------------------------------
template<int CIN, int OT, int MODE, bool TANH_OUT, bool STATS, bool OUTAFF,
         typename TIN, typename TOUT>
__global__ __launch_bounds__(256, 2) void conv_k(
    const TIN* __restrict__ X, const float* __restrict__ vglob,
    const float* __restrict__ W, const float* __restrict__ bias,
    const float* __restrict__ insc, const float* __restrict__ insh,
    const float* __restrict__ outsc, const float* __restrict__ outsh,
    TOUT* __restrict__ Y, float* __restrict__ ssum, float* __restrict__ ssq,
    int COUT)
{
    constexpr int PT = 4;
    constexpr int NT = 256 * PT;
    constexpr int CC = (CIN < 128) ? CIN : 128;
    constexpr int XC = (MODE == 2) ? 64 : CIN;
    __shared__ __align__(16) float Ws[CC][OT];
    __shared__ float lsum[OT];
    __shared__ float lsq[OT];

    const int tid = threadIdx.x;
    const int tile = blockIdx.y;
    const int b = (tile * NT) / NPTS;
    const int n = (tile * NT) % NPTS + tid * PT;
    const int obase = blockIdx.x * OT;

    if (STATS) {
        for (int i = tid; i < OT; i += 256) { lsum[i] = 0.f; lsq[i] = 0.f; }
    }

    float acc[OT][PT];
#pragma unroll
    for (int o = 0; o < OT; ++o)
#pragma unroll
        for (int p = 0; p < PT; ++p) acc[o][p] = 0.f;

    const TIN* Xb = X + (size_t)b * XC * NPTS;

    for (int c0 = 0; c0 < CIN; c0 += CC) {
        for (int i = tid; i < CC * OT; i += 256) {
            int c = i % CC, o = i / CC;
            int oo = obase + o;
            Ws[c][o] = (oo < COUT) ? W[(size_t)oo * CIN + (c0 + c)] : 0.f;
        }
        __syncthreads();
#pragma unroll 2
        for (int c = 0; c < CC; ++c) {
            float xv[PT];
            if (MODE == 2 && (c0 + c) < 32) {
                float gv = vglob[b * 32 + (c0 + c)];
#pragma unroll
                for (int p = 0; p < PT; ++p) xv[p] = gv;
            } else {
                const int cx = (MODE == 2) ? (c0 + c - 32) : (c0 + c);
                if constexpr (std::is_same<TIN, __half>::value) {
                    H4 t = *(const H4*)(Xb + (size_t)cx * NPTS + n);
                    xv[0] = __low2float(t.a); xv[1] = __high2float(t.a);
                    xv[2] = __low2float(t.b); xv[3] = __high2float(t.b);
                } else {
                    float4 t = *(const float4*)(Xb + (size_t)cx * NPTS + n);
                    xv[0] = t.x; xv[1] = t.y; xv[2] = t.z; xv[3] = t.w;
                }
                if (MODE == 1) {
                    float s = insc[cx], h = insh[cx];
#pragma unroll
                    for (int p = 0; p < PT; ++p)
                        xv[p] = fmaxf(fmaf(xv[p], s, h), 0.f);
                }
            }
            const float4* wrow = (const float4*)(&Ws[c][0]);
#pragma unroll
            for (int o4 = 0; o4 < OT / 4; ++o4) {
                float4 w = wrow[o4];
#pragma unroll
                for (int p = 0; p < PT; ++p) {
                    acc[o4 * 4 + 0][p] = fmaf(w.x, xv[p], acc[o4 * 4 + 0][p]);
                    acc[o4 * 4 + 1][p] = fmaf(w.y, xv[p], acc[o4 * 4 + 1][p]);
                    acc[o4 * 4 + 2][p] = fmaf(w.z, xv[p], acc[o4 * 4 + 2][p]);
                    acc[o4 * 4 + 3][p] = fmaf(w.w, xv[p], acc[o4 * 4 + 3][p]);
                }
            }
        }
        __syncthreads();
    }

#pragma unroll
    for (int o = 0; o < OT; ++o) {
        const int oo = obase + o;
        if (oo < COUT) {
            float v[PT];
#pragma unroll
            for (int p = 0; p < PT; ++p) v[p] = acc[o][p];
            if (OUTAFF) {
                float s = outsc[oo], h = outsh[oo];
#pragma unroll
                for (int p = 0; p < PT; ++p) v[p] = fmaxf(fmaf(v[p], s, h), 0.f);
            }
            if (TANH_OUT) {
                float bb = bias[oo];
#pragma unroll
                for (int p = 0; p < PT; ++p) v[p] = tanhf(v[p] + bb);
            }
            const size_t ofs = ((size_t)b * COUT + oo) * NPTS + n;
            if constexpr (std::is_same<TOUT, __half>::value) {
                H4 t; t.a = __floats2half2_rn(v[0], v[1]);
                t.b = __floats2half2_rn(v[2], v[3]);
                *(H4*)(Y + ofs) = t;
            } else {
                *(float4*)(Y + ofs) = make_float4(v[0], v[1], v[2], v[3]);
            }
            if (STATS) {
                float s = v[0] + v[1] + v[2] + v[3];
                float q = fmaf(v[0], v[0], fmaf(v[1], v[1], fmaf(v[2], v[2], v[3] * v[3])));
#pragma unroll
                for (int d = 32; d >= 1; d >>= 1) {
                    s += __shfl_xor(s, d, 64);
                    q += __shfl_xor(q, d, 64);
                }
                if ((tid & 63) == 0) {
                    atomicAdd(&lsum[o], s);
                    atomicAdd(&lsq[o], q);
                }
            }
        }
    }
    if (STATS) {
        __syncthreads();
        for (int i = tid; i < OT; i += 256) {
            int oo = obase + i;
            if (oo < COUT) {
                atomicAdd(&ssum[oo], lsum[i]);
                atomicAdd(&ssq[oo], lsq[i]);
            }
        }
    }
}

// per-channel BN fold: scale = g/sqrt(var+eps), shift = be - mean*scale
__global__ void bnstats_k(const float* __restrict__ ssum, const float* __restrict__ ssq,
                          const float* __restrict__ g, const float* __restrict__ be,
                          float* __restrict__ scale, float* __restrict__ shift, int C)
{
    int c = blockIdx.x * blockDim.x + threadIdx.x;
    if (c >= C) return;
    const float inv = 1.0f / (float)BNTOT;
    float m = ssum[c] * inv;
    float var = fmaf(ssq[c], inv, -m * m);
    float sc = g[c] / sqrtf(var + 1e-5f);
    scale[c] = sc;
    shift[c] = fmaf(-m, sc, be[c]);
}

// SoftPool (UNCHANGED): stable 16-smallest per (b,k), then gather-dot.
__global__ __launch_bounds__(256) void softpool_k(
    const float* __restrict__ y3, const float* __restrict__ sc3,
    const float* __restrict__ sh3, const float* __restrict__ w9,
    const float* __restrict__ b9, float* __restrict__ vout)
{
    extern __shared__ float vals[];
    __shared__ int sidx[NP];
    __shared__ float wv[4];
    __shared__ int wi[4];
    __shared__ float ps[4];

    const int tid = threadIdx.x;
    const int b = blockIdx.x >> 5;
    const int k = blockIdx.x & 31;

    const float* src = y3 + ((size_t)b * 32 + k) * NPTS;
    const float sck = sc3[k], shk = sh3[k];
    for (int i = tid; i < NPTS; i += 256) vals[i] = fmaf(src[i], sck, shk);
    __syncthreads();

    for (int p = 0; p < NP; ++p) {
        float bv = INFINITY;
        int bi = 0x7fffffff;
        for (int i = tid; i < NPTS; i += 256) {
            float x = vals[i];
            if (x < bv) { bv = x; bi = i; }
        }
#pragma unroll
        for (int d = 32; d >= 1; d >>= 1) {
            float ov = __shfl_xor(bv, d, 64);
            int oi = __shfl_xor(bi, d, 64);
            if (ov < bv || (ov == bv && oi < bi)) { bv = ov; bi = oi; }
        }
        if ((tid & 63) == 0) { wv[tid >> 6] = bv; wi[tid >> 6] = bi; }
        __syncthreads();
        if (tid == 0) {
            for (int w = 1; w < 4; ++w)
                if (wv[w] < bv || (wv[w] == bv && wi[w] < bi)) { bv = wv[w]; bi = wi[w]; }
            sidx[p] = bi;
            vals[bi] = INFINITY;
        }
        __syncthreads();
    }

    float part = 0.f;
    for (int i = tid; i < 32 * NP; i += 256) {
        int c = i >> 4, p = i & 15;
        float h = fmaf(y3[((size_t)b * 32 + c) * NPTS + sidx[p]], sc3[c], sh3[c]);
        part += w9[c * NP + p] * h;
    }
#pragma unroll
    for (int d = 32; d >= 1; d >>= 1) part += __shfl_xor(part, d, 64);
    if ((tid & 63) == 0) ps[tid >> 6] = part;
    __syncthreads();
    if (tid == 0) vout[b * 32 + k] = ps[0] + ps[1] + ps[2] + ps[3] + b9[0];
}

// ---------------------------------------------------------------------------
// h1T[b][n][64] fp16 = relu(bn1(y1[b][64][n])), via LDS transpose; also S1b
// per-(b,c) sums. Grid: 16*256 blocks (64-n tile each).
// ---------------------------------------------------------------------------
__global__ __launch_bounds__(256) void transformT_k(
    const float* __restrict__ y1, const float* __restrict__ sc,
    const float* __restrict__ sh, f16* __restrict__ h1T, float* __restrict__ S1b)
{
    __shared__ float arr[64][65];
    __shared__ float s1loc[64];
    const int tid = threadIdx.x;
    const int b = blockIdx.x >> 8;
    const int n0 = (blockIdx.x & 255) * 64;
    if (tid < 64) s1loc[tid] = 0.f;

    const int c = tid >> 2, j4 = tid & 3;
    const float scv = sc[c], shv = sh[c];
    const float* src = y1 + ((size_t)b * 64 + c) * NPTS + n0 + j4 * 16;
    float ls = 0.f;
#pragma unroll
    for (int j = 0; j < 4; ++j) {
        float4 v = *(const float4*)(src + j * 4);
        float r0 = fmaxf(fmaf(v.x, scv, shv), 0.f);
        float r1 = fmaxf(fmaf(v.y, scv, shv), 0.f);
        float r2 = fmaxf(fmaf(v.z, scv, shv), 0.f);
        float r3 = fmaxf(fmaf(v.w, scv, shv), 0.f);
        arr[j4 * 16 + j * 4 + 0][c] = r0;
        arr[j4 * 16 + j * 4 + 1][c] = r1;
        arr[j4 * 16 + j * 4 + 2][c] = r2;
        arr[j4 * 16 + j * 4 + 3][c] = r3;
        ls += (r0 + r1) + (r2 + r3);
    }
    ls += __shfl_xor(ls, 1, 64);
    ls += __shfl_xor(ls, 2, 64);
    if (j4 == 0) atomicAdd(&s1loc[c], ls);
    __syncthreads();

    const int n = tid >> 2, cj = (tid & 3) * 16;
    f16x8 h0, h1v;
#pragma unroll
    for (int jj = 0; jj < 8; ++jj) h0[jj] = (f16)arr[n][cj + jj];
#pragma unroll
    for (int jj = 0; jj < 8; ++jj) h1v[jj] = (f16)arr[n][cj + 8 + jj];
    f16* dst = h1T + ((size_t)b * NPTS + n0 + n) * 64 + cj;
    *(f16x8*)(dst) = h0;
    *(f16x8*)(dst + 8) = h1v;

    if (tid < 64) atomicAdd(&S1b[b * 64 + tid], s1loc[tid]);
}

// M[i][j] = sum over (b,n) of h1T[.,i]*h1T[.,j]. Grid: 128 blocks (b, n-slab/8).
__global__ __launch_bounds__(256) void syrkT_k(const f16* __restrict__ h1T,
                                               float* __restrict__ M)
{
    __shared__ float hs[128][65];
    const int tid = threadIdx.x;
    const int b = blockIdx.x >> 3;
    const int slab = blockIdx.x & 7;
    const int i0 = (tid >> 4) * 4, j0 = (tid & 15) * 4;
    float acc[4][4] = {};
    for (int st = 0; st < 16; ++st) {
        const int n0 = slab * 2048 + st * 128;
        __syncthreads();
        const f16* row = h1T + ((size_t)b * NPTS + n0 + (tid >> 1)) * 64 + (tid & 1) * 32;
#pragma unroll
        for (int i = 0; i < 4; ++i) {
            f16x8 v = *(const f16x8*)(row + i * 8);
#pragma unroll
            for (int jj = 0; jj < 8; ++jj)
                hs[tid >> 1][(tid & 1) * 32 + i * 8 + jj] = (float)v[jj];
        }
        __syncthreads();
        for (int p = 0; p < 128; ++p) {
            float xi[4], xj[4];
#pragma unroll
            for (int ii = 0; ii < 4; ++ii) xi[ii] = hs[p][i0 + ii];
#pragma unroll
            for (int jj = 0; jj < 4; ++jj) xj[jj] = hs[p][j0 + jj];
#pragma unroll
            for (int ii = 0; ii < 4; ++ii)
#pragma unroll
                for (int jj = 0; jj < 4; ++jj)
                    acc[ii][jj] = fmaf(xi[ii], xj[jj], acc[ii][jj]);
        }
    }
#pragma unroll
    for (int ii = 0; ii < 4; ++ii)
#pragma unroll
        for (int jj = 0; jj < 4; ++jj)
            atomicAdd(&M[(i0 + ii) * 64 + (j0 + jj)], acc[ii][jj]);
}

// BN4 from input moments; also emits per-(b,o) fused shift:
//   shift4b[b][o] = sc4[o]*g_ob + (be - mean*sc4), where g_ob = W4g . vv[b]
__global__ void bnstats45_k(const float* __restrict__ w4, const float* __restrict__ vv,
                            const float* __restrict__ S1b, const float* __restrict__ M,
                            const float* __restrict__ g, const float* __restrict__ be,
                            float* __restrict__ sc4, float* __restrict__ shift4b)
{
    __shared__ float vvL[512], sbL[1024], ML[4096];
    const int tid = threadIdx.x;
    for (int i = tid; i < 512; i += 512) vvL[i] = vv[i];
    for (int i = tid; i < 1024; i += 512) sbL[i] = S1b[i];
    for (int i = tid; i < 4096; i += 512) ML[i] = M[i];
    __syncthreads();
    const int o = tid;
    float wg[32], wh[64];
#pragma unroll
    for (int i = 0; i < 32; ++i) wg[i] = w4[o * 96 + i];
#pragma unroll
    for (int j = 0; j < 64; ++j) wh[j] = w4[o * 96 + 32 + j];
    float gbv[16];
    float sumy = 0.f, sumsq = 0.f;
#pragma unroll
    for (int b = 0; b < 16; ++b) {
        float gb = 0.f, hb = 0.f;
#pragma unroll
        for (int i = 0; i < 32; ++i) gb = fmaf(wg[i], vvL[b * 32 + i], gb);
#pragma unroll
        for (int j = 0; j < 64; ++j) hb = fmaf(wh[j], sbL[b * 64 + j], hb);
        gbv[b] = gb;
        sumy += (float)NPTS * gb + hb;
        sumsq += (float)NPTS * gb * gb + 2.f * gb * hb;
    }
    for (int j = 0; j < 64; ++j) {
        float t = 0.f;
#pragma unroll
        for (int j2 = 0; j2 < 64; ++j2) t = fmaf(ML[j * 64 + j2], wh[j2], t);
        sumsq = fmaf(wh[j], t, sumsq);
    }
    const float inv = 1.0f / (float)BNTOT;
    float m = sumy * inv;
    float var = fmaf(sumsq, inv, -m * m);
    float s = g[o] / sqrtf(var + 1e-5f);
    float sh4v = fmaf(-m, s, be[o]);
    sc4[o] = s;
#pragma unroll
    for (int b = 0; b < 16; ++b)
        shift4b[b * 512 + o] = fmaf(gbv[b], s, sh4v);
}

// fp32 -> fp16 weight conversion (optionally a column slice of src)
__global__ void wcvt_k(const float* __restrict__ src, f16* __restrict__ dst,
                       int rows, int cols, int srcStride, int srcOff)
{
    int i = blockIdx.x * 256 + threadIdx.x;
    if (i < rows * cols) {
        int r = i / cols, c = i % cols;
        dst[i] = (f16)src[(size_t)r * srcStride + srcOff + c];
    }
}

// ---------------------------------------------------------------------------
// MFMA 1x1-conv: D[n][m] = sum_k Wh[m][k] * Xt[n][k]   (fp16 in, fp32 acc)
// Layouts (v_mfma_f32_16x16x32_f16):
//   A (W):  lane holds A[m = lane&15][k = 8*(lane>>4)+i], i=0..7   (16B along K)
//   B (Xt): lane holds B[k = 8*(lane>>4)+i][n = lane&15]           (16B along K)
//   D:      lane reg r -> [m = 4*(lane>>4)+r][n = lane&15]
// Block: 256 thr = 4 waves; wave w covers n in [blk*64 + w*16, +16), m in
// [m0, m0+MT*16). INAFF: producer BN+ReLU on B load. OUTAFF: per-(b,m)
// fused scale/shift + ReLU. STATS: raw-output per-m sum/sumsq.
// ---------------------------------------------------------------------------
template<int MT, int KSTEPS, bool INAFF, bool OUTAFF, bool STATS>
__global__ __launch_bounds__(256, 4) void mconv_k(
    const f16* __restrict__ Xt, const f16* __restrict__ Wh,
    const float* __restrict__ insc, const float* __restrict__ insh,
    const float* __restrict__ outsc, const float* __restrict__ outshB,
    f16* __restrict__ Y, float* __restrict__ ssum, float* __restrict__ ssq,
    const int M)
{
    constexpr int K = KSTEPS * 32;
    __shared__ float lsum[STATS ? MT * 16 : 1];
    __shared__ float lsq[STATS ? MT * 16 : 1];
    const int tid = threadIdx.x;
    const int w = tid >> 6, l = tid & 63, llo = l & 15, lhi = l >> 4;
    if (STATS) {
        for (int i = tid; i < MT * 16; i += 256) { lsum[i] = 0.f; lsq[i] = 0.f; }
        __syncthreads();
    }
    const int bl = blockIdx.y >> 8;
    const int nloc = (blockIdx.y & 255) * 64 + w * 16 + llo;
    const size_t nrow = (size_t)bl * NPTS + nloc;
    const int m0 = blockIdx.x * (MT * 16);

    const f16* xrow = Xt + nrow * K;
    const f16* wbase = Wh + (size_t)(m0 + llo) * K + lhi * 8;

    f32x4 acc[MT];
#pragma unroll
    for (int mt = 0; mt < MT; ++mt) acc[mt] = (f32x4){0.f, 0.f, 0.f, 0.f};

    for (int ks = 0; ks < KSTEPS; ++ks) {
        const int kb = ks * 32 + lhi * 8;
        f16x8 bf = *(const f16x8*)(xrow + kb);
        if (INAFF) {
            const float4 s0 = *(const float4*)(insc + kb);
            const float4 s1 = *(const float4*)(insc + kb + 4);
            const float4 h0 = *(const float4*)(insh + kb);
            const float4 h1v = *(const float4*)(insh + kb + 4);
            f16x8 nb;
            nb[0] = (f16)fmaxf(fmaf((float)bf[0], s0.x, h0.x), 0.f);
            nb[1] = (f16)fmaxf(fmaf((float)bf[1], s0.y, h0.y), 0.f);
            nb[2] = (f16)fmaxf(fmaf((float)bf[2], s0.z, h0.z), 0.f);
            nb[3] = (f16)fmaxf(fmaf((float)bf[3], s0.w, h0.w), 0.f);
            nb[4] = (f16)fmaxf(fmaf((float)bf[4], s1.x, h1v.x), 0.f);
            nb[5] = (f16)fmaxf(fmaf((float)bf[5], s1.y, h1v.y), 0.f);
            nb[6] = (f16)fmaxf(fmaf((float)bf[6], s1.z, h1v.z), 0.f);
            nb[7] = (f16)fmaxf(fmaf((float)bf[7], s1.w, h1v.w), 0.f);
            bf = nb;
        }
#pragma unroll
        for (int mt = 0; mt < MT; ++mt) {
            f16x8 af = *(const f16x8*)(wbase + (size_t)mt * 16 * K + ks * 32);
            acc[mt] = __builtin_amdgcn_mfma_f32_16x16x32_f16(af, bf, acc[mt], 0, 0, 0);
        }
    }

    f16* yrow = Y + nrow * M + m0;
#pragma unroll
    for (int mt = 0; mt < MT; ++mt) {
        const int mloc = mt * 16 + 4 * lhi;
        float v0 = acc[mt][0], v1 = acc[mt][1], v2 = acc[mt][2], v3 = acc[mt][3];
        if (OUTAFF) {
            float4 s = *(const float4*)(outsc + m0 + mloc);
            float4 h = *(const float4*)(outshB + (size_t)bl * M + m0 + mloc);
            v0 = fmaxf(fmaf(v0, s.x, h.x), 0.f);
            v1 = fmaxf(fmaf(v1, s.y, h.y), 0.f);
            v2 = fmaxf(fmaf(v2, s.z, h.z), 0.f);
            v3 = fmaxf(fmaf(v3, s.w, h.w), 0.f);
        }
        F16x4 o;
        o.v[0] = (f16)v0; o.v[1] = (f16)v1; o.v[2] = (f16)v2; o.v[3] = (f16)v3;
        *(F16x4*)(yrow + mloc) = o;
        if (STATS) {
            float s0 = v0, s1 = v1, s2 = v2, s3 = v3;
            float q0 = v0 * v0, q1 = v1 * v1, q2 = v2 * v2, q3 = v3 * v3;
#pragma unroll
            for (int d = 1; d < 16; d <<= 1) {
                s0 += __shfl_xor(s0, d, 64); q0 += __shfl_xor(q0, d, 64);
                s1 += __shfl_xor(s1, d, 64); q1 += __shfl_xor(q1, d, 64);
                s2 += __shfl_xor(s2, d, 64); q2 += __shfl_xor(q2, d, 64);
                s3 += __shfl_xor(s3, d, 64); q3 += __shfl_xor(q3, d, 64);
            }
            if (llo == 0) {
                atomicAdd(&lsum[mloc + 0], s0); atomicAdd(&lsq[mloc + 0], q0);
                atomicAdd(&lsum[mloc + 1], s1); atomicAdd(&lsq[mloc + 1], q1);
                atomicAdd(&lsum[mloc + 2], s2); atomicAdd(&lsq[mloc + 2], q2);
                atomicAdd(&lsum[mloc + 3], s3); atomicAdd(&lsq[mloc + 3], q3);
            }
        }
    }
    if (STATS) {
        __syncthreads();
        for (int i = tid; i < MT * 16; i += 256) {
            atomicAdd(&ssum[m0 + i], lsum[i]);
            atomicAdd(&ssq[m0 + i], lsq[i]);
        }
    }
}

// conv7: out[b][o][n] = tanh(b7 + sum_c w7[o][c]*relu(bn6(y6T[n][c])))
__global__ __launch_bounds__(256) void conv7T_k(
    const f16* __restrict__ y6T, const float* __restrict__ sc6,
    const float* __restrict__ sh6, const float* __restrict__ w7,
    const float* __restrict__ b7, float* __restrict__ out)
{
    __shared__ float wsc[128], wsh[128], ww[384];
    const int tid = threadIdx.x;
    if (tid < 128) { wsc[tid] = sc6[tid]; wsh[tid] = sh6[tid]; }
    for (int i = tid; i < 384; i += 256) ww[i] = w7[i];
    __syncthreads();
    const int gid = blockIdx.x * 256 + tid;
    const int b = gid >> 14, nl = gid & 16383;
    const f16* row = y6T + (size_t)gid * 128;
    float a0 = 0.f, a1 = 0.f, a2 = 0.f;
    for (int c8 = 0; c8 < 128; c8 += 8) {
        f16x8 v8 = *(const f16x8*)(row + c8);
#pragma unroll
        for (int j = 0; j < 8; ++j) {
            float hv = fmaxf(fmaf((float)v8[j], wsc[c8 + j], wsh[c8 + j]), 0.f);
            a0 = fmaf(ww[c8 + j], hv, a0);
            a1 = fmaf(ww[128 + c8 + j], hv, a1);
            a2 = fmaf(ww[256 + c8 + j], hv, a2);
        }
    }
    const float bv = b7[0];
    out[((size_t)b * 3 + 0) * NPTS + nl] = tanhf(a0 + bv);
    out[((size_t)b * 3 + 1) * NPTS + nl] = tanhf(a1 + bv);
    out[((size_t)b * 3 + 2) * NPTS + nl] = tanhf(a2 + bv);
}

// Diagnostic fallback
__global__ void fill_k(float* __restrict__ out, int nsize, float val)
{
    int i = blockIdx.x * 256 + threadIdx.x;
    if (i < nsize) out[i] = val;
}

extern "C" void kernel_launch(void* const* d_in, const int* in_sizes, int n_in,
                              void* d_out, int out_size, void* d_ws, size_t ws_size,
                              hipStream_t stream)
{
    const float* x   = (const float*)d_in[0];
    const float* w1  = (const float*)d_in[1];
    const float* g1  = (const float*)d_in[3];
    const float* be1 = (const float*)d_in[4];
    const float* w2  = (const float*)d_in[5];
    const float* g2  = (const float*)d_in[7];
    const float* be2 = (const float*)d_in[8];
    const float* w3  = (const float*)d_in[9];
    const float* g3  = (const float*)d_in[11];
    const float* be3 = (const float*)d_in[12];
    const float* w9  = (const float*)d_in[13];
    const float* b9  = (const float*)d_in[14];
    const float* w4  = (const float*)d_in[15];
    const float* g4  = (const float*)d_in[17];
    const float* be4 = (const float*)d_in[18];
    const float* w5  = (const float*)d_in[19];
    const float* g5  = (const float*)d_in[21];
    const float* be5 = (const float*)d_in[22];
    const float* w6  = (const float*)d_in[23];
    const float* g6  = (const float*)d_in[25];
    const float* be6 = (const float*)d_in[26];
    const float* w7  = (const float*)d_in[27];
    const float* b7  = (const float*)d_in[28];
    float* out = (float*)d_out;

    // ---- workspace plan (226 MiB), lifetime-aliased ----
    //  [1,65M):   y1 fp32 -> y4T fp16 (chunk bounce) -> y6T fp16
    //  [65,193M): y2 fp32; after conv3: h1T fp16 [65,97M)
    //  [97,225M): y5T fp16 (written after softpool; q3 overlaps dead y3)
    //  [193,225M):y3 fp32 (dead after softpool)
    //  [225M,..): stats floats + fp16 weight copies
    const size_t MB = 1048576u;
    const size_t need = 226 * MB;
    if (ws_size < need) {
        float val = 1000.0f + (float)(ws_size >> 20);
        fill_k<<<(out_size + 255) / 256, 256, 0, stream>>>(out, out_size, val);
        return;
    }

    char* base = (char*)d_ws;
    float* y1  = (float*)(base + 1 * MB);
    f16*   y4T = (f16*)(base + 1 * MB);
    f16*   y6T = (f16*)(base + 1 * MB);
    float* y2  = (float*)(base + 65 * MB);
    f16*   h1T = (f16*)(base + 65 * MB);
    f16*   y5T = (f16*)(base + 97 * MB);
    float* y3  = (float*)(base + 193 * MB);
    float* sm  = (float*)(base + 225 * MB);
    f16*   w5h = (f16*)(base + 225 * MB + 131072);
    f16*   w6h = w5h + 131072;   // 256*512
    f16*   w4hh = w6h + 32768;   // 128*256; w4hh is 512*64

    float* sum1 = sm + 0,     *sq1 = sm + 512,  *sc1 = sm + 1024, *sh1 = sm + 1536;
    float* sum2 = sm + 2048,  *sq2 = sm + 2560, *sc2 = sm + 3072, *sh2 = sm + 3584;
    float* sum3 = sm + 4096,  *sq3 = sm + 4608, *sc3 = sm + 5120, *sh3 = sm + 5632;
    float* sc4  = sm + 6144;
    float* sum5 = sm + 7168,  *sq5 = sm + 7680, *sc5 = sm + 8192, *sh5 = sm + 8704;
    float* sum6 = sm + 9216,  *sq6 = sm + 9728, *sc6 = sm + 10240,*sh6 = sm + 10752;
    float* vv   = sm + 11264;            // 512
    float* S1b  = sm + 11776;            // 1024
    float* Mh   = sm + 12800;            // 4096
    float* shift4b = sm + 16896;         // 16*512 -> end 25088

    hipMemsetAsync(sm, 0, 16896 * sizeof(float), stream);

    const dim3 blk(256);
    const int tilesF = BNTOT / 1024;     // 256

    // fp16 weight copies (independent of activations)
    wcvt_k<<<(256 * 512 + 255) / 256, blk, 0, stream>>>(w5, w5h, 256, 512, 512, 0);
    wcvt_k<<<(128 * 256 + 255) / 256, blk, 0, stream>>>(w6, w6h, 128, 256, 256, 0);
    wcvt_k<<<(512 * 64 + 255) / 256, blk, 0, stream>>>(w4, w4hh, 512, 64, 96, 32);

    // conv1..conv3 (fp32, bit-identical to passing round)
    conv_k<4, 32, 0, false, true, false, float, float>
        <<<dim3(2, tilesF), blk, 0, stream>>>(x, nullptr, w1, nullptr, nullptr, nullptr,
            nullptr, nullptr, y1, sum1, sq1, 64);
    bnstats_k<<<1, 256, 0, stream>>>(sum1, sq1, g1, be1, sc1, sh1, 64);

    conv_k<64, 32, 1, false, true, false, float, float>
        <<<dim3(4, tilesF), blk, 0, stream>>>(y1, nullptr, w2, nullptr, sc1, sh1,
            nullptr, nullptr, y2, sum2, sq2, 128);
    bnstats_k<<<1, 256, 0, stream>>>(sum2, sq2, g2, be2, sc2, sh2, 128);

    conv_k<128, 32, 1, false, true, false, float, float>
        <<<dim3(1, tilesF), blk, 0, stream>>>(y2, nullptr, w3, nullptr, sc2, sh2,
            nullptr, nullptr, y3, sum3, sq3, 32);
    bnstats_k<<<1, 256, 0, stream>>>(sum3, sq3, g3, be3, sc3, sh3, 32);

    softpool_k<<<512, blk, NPTS * sizeof(float), stream>>>(y3, sc3, sh3, w9, b9, vv);

    // h1T + S1b, SYRK moment, BN4 (with fused per-(b,o) shift)
    transformT_k<<<16 * 256, blk, 0, stream>>>(y1, sc1, sh1, h1T, S1b);
    syrkT_k<<<128, blk, 0, stream>>>(h1T, Mh);
    bnstats45_k<<<1, 512, 0, stream>>>(w4, vv, S1b, Mh, g4, be4, sc4, shift4b);

    // conv4+conv5 in 4 batch-chunks (MFMA); y4T bounce in y1's region
    for (int q = 0; q < 4; ++q) {
        const f16* h1q = h1T + (size_t)q * 4 * NPTS * 64;
        f16* y5q = y5T + (size_t)q * 4 * NPTS * 256;
        // conv4: K=64 -> 512, OUTAFF(sc4, shift4b) per-b, no stats
        mconv_k<16, 2, false, true, false><<<dim3(2, 1024), blk, 0, stream>>>(
            h1q, w4hh, nullptr, nullptr, sc4, shift4b + (size_t)q * 4 * 512,
            y4T, nullptr, nullptr, 512);
        // conv5: K=512 -> 256, raw + stats
        mconv_k<16, 16, false, false, true><<<dim3(1, 1024), blk, 0, stream>>>(
            y4T, w5h, nullptr, nullptr, nullptr, nullptr,
            y5q, sum5, sq5, 256);
    }
    bnstats_k<<<1, 256, 0, stream>>>(sum5, sq5, g5, be5, sc5, sh5, 256);

    // conv6: K=256 -> 128, INAFF(bn5+relu), raw + stats
    mconv_k<8, 8, true, false, true><<<dim3(1, 4096), blk, 0, stream>>>(
        y5T, w6h, sc5, sh5, nullptr, nullptr,
        y6T, sum6, sq6, 128);
    bnstats_k<<<1, 256, 0, stream>>>(sum6, sq6, g6, be6, sc6, sh6, 128);

    // conv7: VALU, bn6+relu on load, tanh out
    conv7T_k<<<BNTOT / 256, blk, 0, stream>>>(y6T, sc6, sh6, w7, b7, out);
}

// Round 7
// 1003.949 us; speedup vs baseline: 2.6663x; 1.6985x over previous
//
#include <hip/hip_runtime.h>
#include <hip/hip_fp16.h>
#include <math.h>
#include <type_traits>

#define NPTS 16384
#define NB 16
#define BNTOT (NB * NPTS)
#define NP 16

typedef _Float16 f16;
typedef __attribute__((ext_vector_type(8))) _Float16 f16x8;
typedef __attribute__((ext_vector_type(4))) float f32x4;

struct alignas(8) H4 { __half2 a, b; };
struct alignas(8) F16x4 { f16 v[4]; };

// ---------------------------------------------------------------------------
// Legacy fp32 VALU conv (UNCHANGED — conv1..conv3 must stay bit-identical:
// SoftPool's argsort selection is chaotic under reordering).
// ---------------------------------------------------------------------------
template<int CIN, int OT, int MODE, bool TANH_OUT, bool STATS, bool OUTAFF,
         typename TIN, typename TOUT>
__global__ __launch_bounds__(256, 2) void conv_k(
    const TIN* __restrict__ X, const float* __restrict__ vglob,
    const float* __restrict__ W, const float* __restrict__ bias,
    const float* __restrict__ insc, const float* __restrict__ insh,
    const float* __restrict__ outsc, const float* __restrict__ outsh,
    TOUT* __restrict__ Y, float* __restrict__ ssum, float* __restrict__ ssq,
    int COUT)
{
    constexpr int PT = 4;
    constexpr int NT = 256 * PT;
    constexpr int CC = (CIN < 128) ? CIN : 128;
    constexpr int XC = (MODE == 2) ? 64 : CIN;
    __shared__ __align__(16) float Ws[CC][OT];
    __shared__ float lsum[OT];
    __shared__ float lsq[OT];

    const int tid = threadIdx.x;
    const int tile = blockIdx.y;
    const int b = (tile * NT) / NPTS;
    const int n = (tile * NT) % NPTS + tid * PT;
    const int obase = blockIdx.x * OT;

    if (STATS) {
        for (int i = tid; i < OT; i += 256) { lsum[i] = 0.f; lsq[i] = 0.f; }
    }

    float acc[OT][PT];
#pragma unroll
    for (int o = 0; o < OT; ++o)
#pragma unroll
        for (int p = 0; p < PT; ++p) acc[o][p] = 0.f;

    const TIN* Xb = X + (size_t)b * XC * NPTS;

    for (int c0 = 0; c0 < CIN; c0 += CC) {
        for (int i = tid; i < CC * OT; i += 256) {
            int c = i % CC, o = i / CC;
            int oo = obase + o;
            Ws[c][o] = (oo < COUT) ? W[(size_t)oo * CIN + (c0 + c)] : 0.f;
        }
        __syncthreads();
#pragma unroll 2
        for (int c = 0; c < CC; ++c) {
            float xv[PT];
            if (MODE == 2 && (c0 + c) < 32) {
                float gv = vglob[b * 32 + (c0 + c)];
#pragma unroll
                for (int p = 0; p < PT; ++p) xv[p] = gv;
            } else {
                const int cx = (MODE == 2) ? (c0 + c - 32) : (c0 + c);
                if constexpr (std::is_same<TIN, __half>::value) {
                    H4 t = *(const H4*)(Xb + (size_t)cx * NPTS + n);
                    xv[0] = __low2float(t.a); xv[1] = __high2float(t.a);
                    xv[2] = __low2float(t.b); xv[3] = __high2float(t.b);
                } else {
                    float4 t = *(const float4*)(Xb + (size_t)cx * NPTS + n);
                    xv[0] = t.x; xv[1] = t.y; xv[2] = t.z; xv[3] = t.w;
                }
                if (MODE == 1) {
                    float s = insc[cx], h = insh[cx];
#pragma unroll
                    for (int p = 0; p < PT; ++p)
                        xv[p] = fmaxf(fmaf(xv[p], s, h), 0.f);
                }
            }
            const float4* wrow = (const float4*)(&Ws[c][0]);
#pragma unroll
            for (int o4 = 0; o4 < OT / 4; ++o4) {
                float4 w = wrow[o4];
#pragma unroll
                for (int p = 0; p < PT; ++p) {
                    acc[o4 * 4 + 0][p] = fmaf(w.x, xv[p], acc[o4 * 4 + 0][p]);
                    acc[o4 * 4 + 1][p] = fmaf(w.y, xv[p], acc[o4 * 4 + 1][p]);
                    acc[o4 * 4 + 2][p] = fmaf(w.z, xv[p], acc[o4 * 4 + 2][p]);
                    acc[o4 * 4 + 3][p] = fmaf(w.w, xv[p], acc[o4 * 4 + 3][p]);
                }
            }
        }
        __syncthreads();
    }

#pragma unroll
    for (int o = 0; o < OT; ++o) {
        const int oo = obase + o;
        if (oo < COUT) {
            float v[PT];
#pragma unroll
            for (int p = 0; p < PT; ++p) v[p] = acc[o][p];
            if (OUTAFF) {
                float s = outsc[oo], h = outsh[oo];
#pragma unroll
                for (int p = 0; p < PT; ++p) v[p] = fmaxf(fmaf(v[p], s, h), 0.f);
            }
            if (TANH_OUT) {
                float bb = bias[oo];
#pragma unroll
                for (int p = 0; p < PT; ++p) v[p] = tanhf(v[p] + bb);
            }
            const size_t ofs = ((size_t)b * COUT + oo) * NPTS + n;
            if constexpr (std::is_same<TOUT, __half>::value) {
                H4 t; t.a = __floats2half2_rn(v[0], v[1]);
                t.b = __floats2half2_rn(v[2], v[3]);
                *(H4*)(Y + ofs) = t;
            } else {
                *(float4*)(Y + ofs) = make_float4(v[0], v[1], v[2], v[3]);
            }
            if (STATS) {
                float s = v[0] + v[1] + v[2] + v[3];
                float q = fmaf(v[0], v[0], fmaf(v[1], v[1], fmaf(v[2], v[2], v[3] * v[3])));
#pragma unroll
                for (int d = 32; d >= 1; d >>= 1) {
                    s += __shfl_xor(s, d, 64);
                    q += __shfl_xor(q, d, 64);
                }
                if ((tid & 63) == 0) {
                    atomicAdd(&lsum[o], s);
                    atomicAdd(&lsq[o], q);
                }
            }
        }
    }
    if (STATS) {
        __syncthreads();
        for (int i = tid; i < OT; i += 256) {
            int oo = obase + i;
            if (oo < COUT) {
                atomicAdd(&ssum[oo], lsum[i]);
                atomicAdd(&ssq[oo], lsq[i]);
            }
        }
    }
}

// per-channel BN fold: scale = g/sqrt(var+eps), shift = be - mean*scale
__global__ void bnstats_k(const float* __restrict__ ssum, const float* __restrict__ ssq,
                          const float* __restrict__ g, const float* __restrict__ be,
                          float* __restrict__ scale, float* __restrict__ shift, int C)
{
    int c = blockIdx.x * blockDim.x + threadIdx.x;
    if (c >= C) return;
    const float inv = 1.0f / (float)BNTOT;
    float m = ssum[c] * inv;
    float var = fmaf(ssq[c], inv, -m * m);
    float sc = g[c] / sqrtf(var + 1e-5f);
    scale[c] = sc;
    shift[c] = fmaf(-m, sc, be[c]);
}

// SoftPool (UNCHANGED): stable 16-smallest per (b,k), then gather-dot.
__global__ __launch_bounds__(256) void softpool_k(
    const float* __restrict__ y3, const float* __restrict__ sc3,
    const float* __restrict__ sh3, const float* __restrict__ w9,
    const float* __restrict__ b9, float* __restrict__ vout)
{
    extern __shared__ float vals[];
    __shared__ int sidx[NP];
    __shared__ float wv[4];
    __shared__ int wi[4];
    __shared__ float ps[4];

    const int tid = threadIdx.x;
    const int b = blockIdx.x >> 5;
    const int k = blockIdx.x & 31;

    const float* src = y3 + ((size_t)b * 32 + k) * NPTS;
    const float sck = sc3[k], shk = sh3[k];
    for (int i = tid; i < NPTS; i += 256) vals[i] = fmaf(src[i], sck, shk);
    __syncthreads();

    for (int p = 0; p < NP; ++p) {
        float bv = INFINITY;
        int bi = 0x7fffffff;
        for (int i = tid; i < NPTS; i += 256) {
            float x = vals[i];
            if (x < bv) { bv = x; bi = i; }
        }
#pragma unroll
        for (int d = 32; d >= 1; d >>= 1) {
            float ov = __shfl_xor(bv, d, 64);
            int oi = __shfl_xor(bi, d, 64);
            if (ov < bv || (ov == bv && oi < bi)) { bv = ov; bi = oi; }
        }
        if ((tid & 63) == 0) { wv[tid >> 6] = bv; wi[tid >> 6] = bi; }
        __syncthreads();
        if (tid == 0) {
            for (int w = 1; w < 4; ++w)
                if (wv[w] < bv || (wv[w] == bv && wi[w] < bi)) { bv = wv[w]; bi = wi[w]; }
            sidx[p] = bi;
            vals[bi] = INFINITY;
        }
        __syncthreads();
    }

    float part = 0.f;
    for (int i = tid; i < 32 * NP; i += 256) {
        int c = i >> 4, p = i & 15;
        float h = fmaf(y3[((size_t)b * 32 + c) * NPTS + sidx[p]], sc3[c], sh3[c]);
        part += w9[c * NP + p] * h;
    }
#pragma unroll
    for (int d = 32; d >= 1; d >>= 1) part += __shfl_xor(part, d, 64);
    if ((tid & 63) == 0) ps[tid >> 6] = part;
    __syncthreads();
    if (tid == 0) vout[b * 32 + k] = ps[0] + ps[1] + ps[2] + ps[3] + b9[0];
}

// h1T[b][n][64] fp16 = relu(bn1(y1)), LDS transpose; S1b per-(b,c) sums.
__global__ __launch_bounds__(256) void transformT_k(
    const float* __restrict__ y1, const float* __restrict__ sc,
    const float* __restrict__ sh, f16* __restrict__ h1T, float* __restrict__ S1b)
{
    __shared__ float arr[64][65];
    __shared__ float s1loc[64];
    const int tid = threadIdx.x;
    const int b = blockIdx.x >> 8;
    const int n0 = (blockIdx.x & 255) * 64;
    if (tid < 64) s1loc[tid] = 0.f;

    const int c = tid >> 2, j4 = tid & 3;
    const float scv = sc[c], shv = sh[c];
    const float* src = y1 + ((size_t)b * 64 + c) * NPTS + n0 + j4 * 16;
    float ls = 0.f;
#pragma unroll
    for (int j = 0; j < 4; ++j) {
        float4 v = *(const float4*)(src + j * 4);
        float r0 = fmaxf(fmaf(v.x, scv, shv), 0.f);
        float r1 = fmaxf(fmaf(v.y, scv, shv), 0.f);
        float r2 = fmaxf(fmaf(v.z, scv, shv), 0.f);
        float r3 = fmaxf(fmaf(v.w, scv, shv), 0.f);
        arr[j4 * 16 + j * 4 + 0][c] = r0;
        arr[j4 * 16 + j * 4 + 1][c] = r1;
        arr[j4 * 16 + j * 4 + 2][c] = r2;
        arr[j4 * 16 + j * 4 + 3][c] = r3;
        ls += (r0 + r1) + (r2 + r3);
    }
    ls += __shfl_xor(ls, 1, 64);
    ls += __shfl_xor(ls, 2, 64);
    if (j4 == 0) atomicAdd(&s1loc[c], ls);
    __syncthreads();

    const int n = tid >> 2, cj = (tid & 3) * 16;
    f16x8 h0, h1v;
#pragma unroll
    for (int jj = 0; jj < 8; ++jj) h0[jj] = (f16)arr[n][cj + jj];
#pragma unroll
    for (int jj = 0; jj < 8; ++jj) h1v[jj] = (f16)arr[n][cj + 8 + jj];
    f16* dst = h1T + ((size_t)b * NPTS + n0 + n) * 64 + cj;
    *(f16x8*)(dst) = h0;
    *(f16x8*)(dst + 8) = h1v;

    if (tid < 64) atomicAdd(&S1b[b * 64 + tid], s1loc[tid]);
}

// M[i][j] = sum over (b,n) of h1T[.,i]*h1T[.,j].
__global__ __launch_bounds__(256) void syrkT_k(const f16* __restrict__ h1T,
                                               float* __restrict__ M)
{
    __shared__ float hs[128][65];
    const int tid = threadIdx.x;
    const int b = blockIdx.x >> 3;
    const int slab = blockIdx.x & 7;
    const int i0 = (tid >> 4) * 4, j0 = (tid & 15) * 4;
    float acc[4][4] = {};
    for (int st = 0; st < 16; ++st) {
        const int n0 = slab * 2048 + st * 128;
        __syncthreads();
        const f16* row = h1T + ((size_t)b * NPTS + n0 + (tid >> 1)) * 64 + (tid & 1) * 32;
#pragma unroll
        for (int i = 0; i < 4; ++i) {
            f16x8 v = *(const f16x8*)(row + i * 8);
#pragma unroll
            for (int jj = 0; jj < 8; ++jj)
                hs[tid >> 1][(tid & 1) * 32 + i * 8 + jj] = (float)v[jj];
        }
        __syncthreads();
        for (int p = 0; p < 128; ++p) {
            float xi[4], xj[4];
#pragma unroll
            for (int ii = 0; ii < 4; ++ii) xi[ii] = hs[p][i0 + ii];
#pragma unroll
            for (int jj = 0; jj < 4; ++jj) xj[jj] = hs[p][j0 + jj];
#pragma unroll
            for (int ii = 0; ii < 4; ++ii)
#pragma unroll
                for (int jj = 0; jj < 4; ++jj)
                    acc[ii][jj] = fmaf(xi[ii], xj[jj], acc[ii][jj]);
        }
    }
#pragma unroll
    for (int ii = 0; ii < 4; ++ii)
#pragma unroll
        for (int jj = 0; jj < 4; ++jj)
            atomicAdd(&M[(i0 + ii) * 64 + (j0 + jj)], acc[ii][jj]);
}

// BN4 from input moments; emits per-(b,o) fused shift.
__global__ void bnstats45_k(const float* __restrict__ w4, const float* __restrict__ vv,
                            const float* __restrict__ S1b, const float* __restrict__ M,
                            const float* __restrict__ g, const float* __restrict__ be,
                            float* __restrict__ sc4, float* __restrict__ shift4b)
{
    __shared__ float vvL[512], sbL[1024], ML[4096];
    const int tid = threadIdx.x;
    for (int i = tid; i < 512; i += 512) vvL[i] = vv[i];
    for (int i = tid; i < 1024; i += 512) sbL[i] = S1b[i];
    for (int i = tid; i < 4096; i += 512) ML[i] = M[i];
    __syncthreads();
    const int o = tid;
    float wg[32], wh[64];
#pragma unroll
    for (int i = 0; i < 32; ++i) wg[i] = w4[o * 96 + i];
#pragma unroll
    for (int j = 0; j < 64; ++j) wh[j] = w4[o * 96 + 32 + j];
    float gbv[16];
    float sumy = 0.f, sumsq = 0.f;
#pragma unroll
    for (int b = 0; b < 16; ++b) {
        float gb = 0.f, hb = 0.f;
#pragma unroll
        for (int i = 0; i < 32; ++i) gb = fmaf(wg[i], vvL[b * 32 + i], gb);
#pragma unroll
        for (int j = 0; j < 64; ++j) hb = fmaf(wh[j], sbL[b * 64 + j], hb);
        gbv[b] = gb;
        sumy += (float)NPTS * gb + hb;
        sumsq += (float)NPTS * gb * gb + 2.f * gb * hb;
    }
    for (int j = 0; j < 64; ++j) {
        float t = 0.f;
#pragma unroll
        for (int j2 = 0; j2 < 64; ++j2) t = fmaf(ML[j * 64 + j2], wh[j2], t);
        sumsq = fmaf(wh[j], t, sumsq);
    }
    const float inv = 1.0f / (float)BNTOT;
    float m = sumy * inv;
    float var = fmaf(sumsq, inv, -m * m);
    float s = g[o] / sqrtf(var + 1e-5f);
    float sh4v = fmaf(-m, s, be[o]);
    sc4[o] = s;
#pragma unroll
    for (int b = 0; b < 16; ++b)
        shift4b[b * 512 + o] = fmaf(gbv[b], s, sh4v);
}

// fp32 -> fp16 weight conversion (optionally a column slice of src)
__global__ void wcvt_k(const float* __restrict__ src, f16* __restrict__ dst,
                       int rows, int cols, int srcStride, int srcOff)
{
    int i = blockIdx.x * 256 + threadIdx.x;
    if (i < rows * cols) {
        int r = i / cols, c = i % cols;
        dst[i] = (f16)src[(size_t)r * srcStride + srcOff + c];
    }
}

// ---------------------------------------------------------------------------
// LDS-tiled MFMA GEMM: D[n][m] = sum_k Wh[m][k] * Xt[n][k], fp16 in / fp32 acc.
// Tile 128n x 128m, BK=64, 4 waves (2x2), each wave 64x64 (4x4 16x16x32 frags).
// Reg-staged global->LDS with XOR swizzle (sub ^= row&7) -> conflict-free
// ds_read_b128 frag reads (guide §6 G4). Next-K-tile loads issued right after
// the barrier so HBM latency hides under 32 MFMAs (T14 split).
// INAFF: producer BN+ReLU applied at staging (same math as per-frag, 8x cheaper).
// OUTAFF: per-(b,m) scale/shift+ReLU epilogue. STATS: raw per-m sum/sumsq.
// K accumulation order identical to previous round (bitwise-stable absmax).
// ---------------------------------------------------------------------------
#define GLOAD(KT, RA, RB)                                                       \
  {                                                                             \
    const int kb_ = (KT) * 64 + sj * 8;                                         \
    float4 is0, is1, ih0, ih1;                                                  \
    if (INAFF) {                                                                \
      is0 = *(const float4*)(insc + kb_); is1 = *(const float4*)(insc + kb_ + 4); \
      ih0 = *(const float4*)(insh + kb_); ih1 = *(const float4*)(insh + kb_ + 4); \
    }                                                                           \
    _Pragma("unroll")                                                           \
    for (int i_ = 0; i_ < 4; ++i_) {                                            \
      const int r_ = sr + i_ * 32;                                              \
      RA[i_] = *(const f16x8*)(wsrc + (size_t)r_ * K + kb_);                    \
      f16x8 xb = *(const f16x8*)(xsrc + (size_t)r_ * K + kb_);                  \
      if (INAFF) {                                                              \
        f16x8 nb;                                                               \
        nb[0] = (f16)fmaxf(fmaf((float)xb[0], is0.x, ih0.x), 0.f);              \
        nb[1] = (f16)fmaxf(fmaf((float)xb[1], is0.y, ih0.y), 0.f);              \
        nb[2] = (f16)fmaxf(fmaf((float)xb[2], is0.z, ih0.z), 0.f);              \
        nb[3] = (f16)fmaxf(fmaf((float)xb[3], is0.w, ih0.w), 0.f);              \
        nb[4] = (f16)fmaxf(fmaf((float)xb[4], is1.x, ih1.x), 0.f);              \
        nb[5] = (f16)fmaxf(fmaf((float)xb[5], is1.y, ih1.y), 0.f);              \
        nb[6] = (f16)fmaxf(fmaf((float)xb[6], is1.z, ih1.z), 0.f);              \
        nb[7] = (f16)fmaxf(fmaf((float)xb[7], is1.w, ih1.w), 0.f);              \
        xb = nb;                                                                \
      }                                                                         \
      RB[i_] = xb;                                                              \
    }                                                                           \
  }

#define DSWRITE(RA, RB)                                                         \
  {                                                                             \
    _Pragma("unroll")                                                           \
    for (int i_ = 0; i_ < 4; ++i_) {                                            \
      const int r_ = sr + i_ * 32;                                              \
      const int sw_ = sj ^ (r_ & 7);                                            \
      *(f16x8*)(&As[r_ * 64 + sw_ * 8]) = RA[i_];                               \
      *(f16x8*)(&Bs[r_ * 64 + sw_ * 8]) = RB[i_];                               \
    }                                                                           \
  }

template<int KS, bool INAFF, bool OUTAFF, bool STATS>
__global__ __launch_bounds__(256, 2) void gconv_k(
    const f16* __restrict__ Xt, const f16* __restrict__ Wh,
    const float* __restrict__ insc, const float* __restrict__ insh,
    const float* __restrict__ outsc, const float* __restrict__ outshB,
    f16* __restrict__ Y, float* __restrict__ ssum, float* __restrict__ ssq,
    const int M)
{
    constexpr int K = KS * 64;
    __shared__ __align__(16) f16 As[128 * 64];   // [m][k], 16B-sub XOR-swizzled
    __shared__ __align__(16) f16 Bs[128 * 64];   // [n][k], same swizzle
    __shared__ float lsum[128];
    __shared__ float lsq[128];

    const int tid = threadIdx.x;
    const int w = tid >> 6, lane = tid & 63;
    const int llo = lane & 15, lhi = lane >> 4;
    const int wn = w >> 1, wm = w & 1;
    const int n0 = blockIdx.y * 128;
    const int m0 = blockIdx.x * 128;
    const int sr = tid >> 3, sj = tid & 7;       // staging row/sub (rows +32 per i)

    if (STATS && tid < 128) { lsum[tid] = 0.f; lsq[tid] = 0.f; }

    const f16* xsrc = Xt + (size_t)n0 * K;
    const f16* wsrc = Wh + (size_t)m0 * K;

    f32x4 acc[4][4];
#pragma unroll
    for (int nf = 0; nf < 4; ++nf)
#pragma unroll
        for (int mf = 0; mf < 4; ++mf) acc[nf][mf] = (f32x4){0.f, 0.f, 0.f, 0.f};

    f16x8 ra0[4], rb0[4], ra1[4], rb1[4];
    GLOAD(0, ra0, rb0);

#pragma unroll
    for (int kt = 0; kt < KS; ++kt) {
        if ((kt & 1) == 0) { DSWRITE(ra0, rb0); } else { DSWRITE(ra1, rb1); }
        __syncthreads();
        if (kt + 1 < KS) {
            if ((kt & 1) == 0) { GLOAD(kt + 1, ra1, rb1); }
            else               { GLOAD(kt + 1, ra0, rb0); }
        }
#pragma unroll
        for (int ks = 0; ks < 2; ++ks) {
            f16x8 af[4], bf[4];
#pragma unroll
            for (int f = 0; f < 4; ++f) {
                const int ml = wm * 64 + f * 16 + llo;
                af[f] = *(const f16x8*)(&As[ml * 64 + ((ks * 4 + lhi) ^ (ml & 7)) * 8]);
                const int nl = wn * 64 + f * 16 + llo;
                bf[f] = *(const f16x8*)(&Bs[nl * 64 + ((ks * 4 + lhi) ^ (nl & 7)) * 8]);
            }
#pragma unroll
            for (int nf = 0; nf < 4; ++nf)
#pragma unroll
                for (int mf = 0; mf < 4; ++mf)
                    acc[nf][mf] = __builtin_amdgcn_mfma_f32_16x16x32_f16(
                        af[mf], bf[nf], acc[nf][mf], 0, 0, 0);
        }
        __syncthreads();
    }

    // epilogue: lane reg r of frag (nf,mf) -> (n = ..+llo, m = ..+4*lhi+r)
    const int bl = n0 / NPTS;
#pragma unroll
    for (int nf = 0; nf < 4; ++nf) {
        const int n = n0 + wn * 64 + nf * 16 + llo;
        f16* row = Y + (size_t)n * M + m0 + wm * 64;
#pragma unroll
        for (int mf = 0; mf < 4; ++mf) {
            const int moff = mf * 16 + 4 * lhi;
            float v0 = acc[nf][mf][0], v1 = acc[nf][mf][1];
            float v2 = acc[nf][mf][2], v3 = acc[nf][mf][3];
            if (OUTAFF) {
                const int mg = m0 + wm * 64 + moff;
                float4 s = *(const float4*)(outsc + mg);
                float4 h = *(const float4*)(outshB + (size_t)bl * M + mg);
                v0 = fmaxf(fmaf(v0, s.x, h.x), 0.f);
                v1 = fmaxf(fmaf(v1, s.y, h.y), 0.f);
                v2 = fmaxf(fmaf(v2, s.z, h.z), 0.f);
                v3 = fmaxf(fmaf(v3, s.w, h.w), 0.f);
            }
            F16x4 o;
            o.v[0] = (f16)v0; o.v[1] = (f16)v1; o.v[2] = (f16)v2; o.v[3] = (f16)v3;
            *(F16x4*)(row + moff) = o;
        }
    }
    if (STATS) {
#pragma unroll
        for (int mf = 0; mf < 4; ++mf) {
#pragma unroll
            for (int r = 0; r < 4; ++r) {
                float s = acc[0][mf][r] + acc[1][mf][r] + acc[2][mf][r] + acc[3][mf][r];
                float q = fmaf(acc[0][mf][r], acc[0][mf][r],
                          fmaf(acc[1][mf][r], acc[1][mf][r],
                          fmaf(acc[2][mf][r], acc[2][mf][r],
                               acc[3][mf][r] * acc[3][mf][r])));
#pragma unroll
                for (int d = 1; d < 16; d <<= 1) {
                    s += __shfl_xor(s, d, 64);
                    q += __shfl_xor(q, d, 64);
                }
                if (llo == 0) {
                    atomicAdd(&lsum[wm * 64 + mf * 16 + 4 * lhi + r], s);
                    atomicAdd(&lsq [wm * 64 + mf * 16 + 4 * lhi + r], q);
                }
            }
        }
        __syncthreads();
        if (tid < 128) {
            atomicAdd(&ssum[m0 + tid], lsum[tid]);
            atomicAdd(&ssq [m0 + tid], lsq [tid]);
        }
    }
}

// conv7: out[b][o][n] = tanh(b7 + sum_c w7[o][c]*relu(bn6(y6T[n][c])))
__global__ __launch_bounds__(256) void conv7T_k(
    const f16* __restrict__ y6T, const float* __restrict__ sc6,
    const float* __restrict__ sh6, const float* __restrict__ w7,
    const float* __restrict__ b7, float* __restrict__ out)
{
    __shared__ float wsc[128], wsh[128], ww[384];
    const int tid = threadIdx.x;
    if (tid < 128) { wsc[tid] = sc6[tid]; wsh[tid] = sh6[tid]; }
    for (int i = tid; i < 384; i += 256) ww[i] = w7[i];
    __syncthreads();
    const int gid = blockIdx.x * 256 + tid;
    const int b = gid >> 14, nl = gid & 16383;
    const f16* row = y6T + (size_t)gid * 128;
    float a0 = 0.f, a1 = 0.f, a2 = 0.f;
    for (int c8 = 0; c8 < 128; c8 += 8) {
        f16x8 v8 = *(const f16x8*)(row + c8);
#pragma unroll
        for (int j = 0; j < 8; ++j) {
            float hv = fmaxf(fmaf((float)v8[j], wsc[c8 + j], wsh[c8 + j]), 0.f);
            a0 = fmaf(ww[c8 + j], hv, a0);
            a1 = fmaf(ww[128 + c8 + j], hv, a1);
            a2 = fmaf(ww[256 + c8 + j], hv, a2);
        }
    }
    const float bv = b7[0];
    out[((size_t)b * 3 + 0) * NPTS + nl] = tanhf(a0 + bv);
    out[((size_t)b * 3 + 1) * NPTS + nl] = tanhf(a1 + bv);
    out[((size_t)b * 3 + 2) * NPTS + nl] = tanhf(a2 + bv);
}

// Diagnostic fallback
__global__ void fill_k(float* __restrict__ out, int nsize, float val)
{
    int i = blockIdx.x * 256 + threadIdx.x;
    if (i < nsize) out[i] = val;
}

extern "C" void kernel_launch(void* const* d_in, const int* in_sizes, int n_in,
                              void* d_out, int out_size, void* d_ws, size_t ws_size,
                              hipStream_t stream)
{
    const float* x   = (const float*)d_in[0];
    const float* w1  = (const float*)d_in[1];
    const float* g1  = (const float*)d_in[3];
    const float* be1 = (const float*)d_in[4];
    const float* w2  = (const float*)d_in[5];
    const float* g2  = (const float*)d_in[7];
    const float* be2 = (const float*)d_in[8];
    const float* w3  = (const float*)d_in[9];
    const float* g3  = (const float*)d_in[11];
    const float* be3 = (const float*)d_in[12];
    const float* w9  = (const float*)d_in[13];
    const float* b9  = (const float*)d_in[14];
    const float* w4  = (const float*)d_in[15];
    const float* g4  = (const float*)d_in[17];
    const float* be4 = (const float*)d_in[18];
    const float* w5  = (const float*)d_in[19];
    const float* g5  = (const float*)d_in[21];
    const float* be5 = (const float*)d_in[22];
    const float* w6  = (const float*)d_in[23];
    const float* g6  = (const float*)d_in[25];
    const float* be6 = (const float*)d_in[26];
    const float* w7  = (const float*)d_in[27];
    const float* b7  = (const float*)d_in[28];
    float* out = (float*)d_out;

    // ---- workspace plan (226 MiB), lifetime-aliased (unchanged) ----
    const size_t MB = 1048576u;
    const size_t need = 226 * MB;
    if (ws_size < need) {
        float val = 1000.0f + (float)(ws_size >> 20);
        fill_k<<<(out_size + 255) / 256, 256, 0, stream>>>(out, out_size, val);
        return;
    }

    char* base = (char*)d_ws;
    float* y1  = (float*)(base + 1 * MB);
    f16*   y4T = (f16*)(base + 1 * MB);
    f16*   y6T = (f16*)(base + 1 * MB);
    float* y2  = (float*)(base + 65 * MB);
    f16*   h1T = (f16*)(base + 65 * MB);
    f16*   y5T = (f16*)(base + 97 * MB);
    float* y3  = (float*)(base + 193 * MB);
    float* sm  = (float*)(base + 225 * MB);
    f16*   w5h = (f16*)(base + 225 * MB + 131072);
    f16*   w6h = w5h + 131072;   // 256*512
    f16*   w4hh = w6h + 32768;   // 128*256; w4hh is 512*64

    float* sum1 = sm + 0,     *sq1 = sm + 512,  *sc1 = sm + 1024, *sh1 = sm + 1536;
    float* sum2 = sm + 2048,  *sq2 = sm + 2560, *sc2 = sm + 3072, *sh2 = sm + 3584;
    float* sum3 = sm + 4096,  *sq3 = sm + 4608, *sc3 = sm + 5120, *sh3 = sm + 5632;
    float* sc4  = sm + 6144;
    float* sum5 = sm + 7168,  *sq5 = sm + 7680, *sc5 = sm + 8192, *sh5 = sm + 8704;
    float* sum6 = sm + 9216,  *sq6 = sm + 9728, *sc6 = sm + 10240,*sh6 = sm + 10752;
    float* vv   = sm + 11264;            // 512
    float* S1b  = sm + 11776;            // 1024
    float* Mh   = sm + 12800;            // 4096
    float* shift4b = sm + 16896;         // 16*512 -> end 25088

    hipMemsetAsync(sm, 0, 16896 * sizeof(float), stream);

    const dim3 blk(256);
    const int tilesF = BNTOT / 1024;     // 256

    // fp16 weight copies
    wcvt_k<<<(256 * 512 + 255) / 256, blk, 0, stream>>>(w5, w5h, 256, 512, 512, 0);
    wcvt_k<<<(128 * 256 + 255) / 256, blk, 0, stream>>>(w6, w6h, 128, 256, 256, 0);
    wcvt_k<<<(512 * 64 + 255) / 256, blk, 0, stream>>>(w4, w4hh, 512, 64, 96, 32);

    // conv1..conv3 (fp32, bit-identical)
    conv_k<4, 32, 0, false, true, false, float, float>
        <<<dim3(2, tilesF), blk, 0, stream>>>(x, nullptr, w1, nullptr, nullptr, nullptr,
            nullptr, nullptr, y1, sum1, sq1, 64);
    bnstats_k<<<1, 256, 0, stream>>>(sum1, sq1, g1, be1, sc1, sh1, 64);

    conv_k<64, 32, 1, false, true, false, float, float>
        <<<dim3(4, tilesF), blk, 0, stream>>>(y1, nullptr, w2, nullptr, sc1, sh1,
            nullptr, nullptr, y2, sum2, sq2, 128);
    bnstats_k<<<1, 256, 0, stream>>>(sum2, sq2, g2, be2, sc2, sh2, 128);

    conv_k<128, 32, 1, false, true, false, float, float>
        <<<dim3(1, tilesF), blk, 0, stream>>>(y2, nullptr, w3, nullptr, sc2, sh2,
            nullptr, nullptr, y3, sum3, sq3, 32);
    bnstats_k<<<1, 256, 0, stream>>>(sum3, sq3, g3, be3, sc3, sh3, 32);

    softpool_k<<<512, blk, NPTS * sizeof(float), stream>>>(y3, sc3, sh3, w9, b9, vv);

    // h1T + S1b, SYRK moment, BN4 (fused per-(b,o) shift)
    transformT_k<<<16 * 256, blk, 0, stream>>>(y1, sc1, sh1, h1T, S1b);
    syrkT_k<<<128, blk, 0, stream>>>(h1T, Mh);
    bnstats45_k<<<1, 512, 0, stream>>>(w4, vv, S1b, Mh, g4, be4, sc4, shift4b);

    // conv4+conv5 in 4 batch-chunks (tiled MFMA GEMM); y4T bounce in y1 region
    for (int q = 0; q < 4; ++q) {
        const f16* h1q = h1T + (size_t)q * 4 * NPTS * 64;
        f16* y5q = y5T + (size_t)q * 4 * NPTS * 256;
        // conv4: K=64 -> M=512, OUTAFF(sc4, shift4b per-b)
        gconv_k<1, false, true, false><<<dim3(4, 512), blk, 0, stream>>>(
            h1q, w4hh, nullptr, nullptr, sc4, shift4b + (size_t)q * 4 * 512,
            y4T, nullptr, nullptr, 512);
        // conv5: K=512 -> M=256, raw + stats
        gconv_k<8, false, false, true><<<dim3(2, 512), blk, 0, stream>>>(
            y4T, w5h, nullptr, nullptr, nullptr, nullptr,
            y5q, sum5, sq5, 256);
    }
    bnstats_k<<<1, 256, 0, stream>>>(sum5, sq5, g5, be5, sc5, sh5, 256);

    // conv6: K=256 -> M=128, INAFF(bn5+relu at staging), raw + stats
    gconv_k<4, true, false, true><<<dim3(1, 2048), blk, 0, stream>>>(
        y5T, w6h, sc5, sh5, nullptr, nullptr,
        y6T, sum6, sq6, 128);
    bnstats_k<<<1, 256, 0, stream>>>(sum6, sq6, g6, be6, sc6, sh6, 128);

    // conv7: VALU, bn6+relu on load, tanh out
    conv7T_k<<<BNTOT / 256, blk, 0, stream>>>(y6T, sc6, sh6, w7, b7, out);
}

// Round 8
// 911.056 us; speedup vs baseline: 2.9382x; 1.1020x over previous
//
#include <hip/hip_runtime.h>
#include <hip/hip_fp16.h>
#include <math.h>
#include <type_traits>

#define NPTS 16384
#define NB 16
#define BNTOT (NB * NPTS)
#define NP 16

typedef _Float16 f16;
typedef __attribute__((ext_vector_type(8))) _Float16 f16x8;
typedef __attribute__((ext_vector_type(4))) float f32x4;

struct alignas(8) H4 { __half2 a, b; };
struct alignas(8) F16x4 { f16 v[4]; };

// ---------------------------------------------------------------------------
// Legacy fp32 VALU conv (UNCHANGED — conv1..conv3 must stay bit-identical:
// SoftPool's argsort selection is chaotic under reordering).
// ---------------------------------------------------------------------------
template<int CIN, int OT, int MODE, bool TANH_OUT, bool STATS, bool OUTAFF,
         typename TIN, typename TOUT>
__global__ __launch_bounds__(256, 2) void conv_k(
    const TIN* __restrict__ X, const float* __restrict__ vglob,
    const float* __restrict__ W, const float* __restrict__ bias,
    const float* __restrict__ insc, const float* __restrict__ insh,
    const float* __restrict__ outsc, const float* __restrict__ outsh,
    TOUT* __restrict__ Y, float* __restrict__ ssum, float* __restrict__ ssq,
    int COUT)
{
    constexpr int PT = 4;
    constexpr int NT = 256 * PT;
    constexpr int CC = (CIN < 128) ? CIN : 128;
    constexpr int XC = (MODE == 2) ? 64 : CIN;
    __shared__ __align__(16) float Ws[CC][OT];
    __shared__ float lsum[OT];
    __shared__ float lsq[OT];

    const int tid = threadIdx.x;
    const int tile = blockIdx.y;
    const int b = (tile * NT) / NPTS;
    const int n = (tile * NT) % NPTS + tid * PT;
    const int obase = blockIdx.x * OT;

    if (STATS) {
        for (int i = tid; i < OT; i += 256) { lsum[i] = 0.f; lsq[i] = 0.f; }
    }

    float acc[OT][PT];
#pragma unroll
    for (int o = 0; o < OT; ++o)
#pragma unroll
        for (int p = 0; p < PT; ++p) acc[o][p] = 0.f;

    const TIN* Xb = X + (size_t)b * XC * NPTS;

    for (int c0 = 0; c0 < CIN; c0 += CC) {
        for (int i = tid; i < CC * OT; i += 256) {
            int c = i % CC, o = i / CC;
            int oo = obase + o;
            Ws[c][o] = (oo < COUT) ? W[(size_t)oo * CIN + (c0 + c)] : 0.f;
        }
        __syncthreads();
#pragma unroll 2
        for (int c = 0; c < CC; ++c) {
            float xv[PT];
            if (MODE == 2 && (c0 + c) < 32) {
                float gv = vglob[b * 32 + (c0 + c)];
#pragma unroll
                for (int p = 0; p < PT; ++p) xv[p] = gv;
            } else {
                const int cx = (MODE == 2) ? (c0 + c - 32) : (c0 + c);
                if constexpr (std::is_same<TIN, __half>::value) {
                    H4 t = *(const H4*)(Xb + (size_t)cx * NPTS + n);
                    xv[0] = __low2float(t.a); xv[1] = __high2float(t.a);
                    xv[2] = __low2float(t.b); xv[3] = __high2float(t.b);
                } else {
                    float4 t = *(const float4*)(Xb + (size_t)cx * NPTS + n);
                    xv[0] = t.x; xv[1] = t.y; xv[2] = t.z; xv[3] = t.w;
                }
                if (MODE == 1) {
                    float s = insc[cx], h = insh[cx];
#pragma unroll
                    for (int p = 0; p < PT; ++p)
                        xv[p] = fmaxf(fmaf(xv[p], s, h), 0.f);
                }
            }
            const float4* wrow = (const float4*)(&Ws[c][0]);
#pragma unroll
            for (int o4 = 0; o4 < OT / 4; ++o4) {
                float4 w = wrow[o4];
#pragma unroll
                for (int p = 0; p < PT; ++p) {
                    acc[o4 * 4 + 0][p] = fmaf(w.x, xv[p], acc[o4 * 4 + 0][p]);
                    acc[o4 * 4 + 1][p] = fmaf(w.y, xv[p], acc[o4 * 4 + 1][p]);
                    acc[o4 * 4 + 2][p] = fmaf(w.z, xv[p], acc[o4 * 4 + 2][p]);
                    acc[o4 * 4 + 3][p] = fmaf(w.w, xv[p], acc[o4 * 4 + 3][p]);
                }
            }
        }
        __syncthreads();
    }

#pragma unroll
    for (int o = 0; o < OT; ++o) {
        const int oo = obase + o;
        if (oo < COUT) {
            float v[PT];
#pragma unroll
            for (int p = 0; p < PT; ++p) v[p] = acc[o][p];
            if (OUTAFF) {
                float s = outsc[oo], h = outsh[oo];
#pragma unroll
                for (int p = 0; p < PT; ++p) v[p] = fmaxf(fmaf(v[p], s, h), 0.f);
            }
            if (TANH_OUT) {
                float bb = bias[oo];
#pragma unroll
                for (int p = 0; p < PT; ++p) v[p] = tanhf(v[p] + bb);
            }
            const size_t ofs = ((size_t)b * COUT + oo) * NPTS + n;
            if constexpr (std::is_same<TOUT, __half>::value) {
                H4 t; t.a = __floats2half2_rn(v[0], v[1]);
                t.b = __floats2half2_rn(v[2], v[3]);
                *(H4*)(Y + ofs) = t;
            } else {
                *(float4*)(Y + ofs) = make_float4(v[0], v[1], v[2], v[3]);
            }
            if (STATS) {
                float s = v[0] + v[1] + v[2] + v[3];
                float q = fmaf(v[0], v[0], fmaf(v[1], v[1], fmaf(v[2], v[2], v[3] * v[3])));
#pragma unroll
                for (int d = 32; d >= 1; d >>= 1) {
                    s += __shfl_xor(s, d, 64);
                    q += __shfl_xor(q, d, 64);
                }
                if ((tid & 63) == 0) {
                    atomicAdd(&lsum[o], s);
                    atomicAdd(&lsq[o], q);
                }
            }
        }
    }
    if (STATS) {
        __syncthreads();
        for (int i = tid; i < OT; i += 256) {
            int oo = obase + i;
            if (oo < COUT) {
                atomicAdd(&ssum[oo], lsum[i]);
                atomicAdd(&ssq[oo], lsq[i]);
            }
        }
    }
}

// per-channel BN fold: scale = g/sqrt(var+eps), shift = be - mean*scale
__global__ void bnstats_k(const float* __restrict__ ssum, const float* __restrict__ ssq,
                          const float* __restrict__ g, const float* __restrict__ be,
                          float* __restrict__ scale, float* __restrict__ shift, int C)
{
    int c = blockIdx.x * blockDim.x + threadIdx.x;
    if (c >= C) return;
    const float inv = 1.0f / (float)BNTOT;
    float m = ssum[c] * inv;
    float var = fmaf(ssq[c], inv, -m * m);
    float sc = g[c] / sqrtf(var + 1e-5f);
    scale[c] = sc;
    shift[c] = fmaf(-m, sc, be[c]);
}

// SoftPool (UNCHANGED): stable 16-smallest per (b,k), then gather-dot.
__global__ __launch_bounds__(256) void softpool_k(
    const float* __restrict__ y3, const float* __restrict__ sc3,
    const float* __restrict__ sh3, const float* __restrict__ w9,
    const float* __restrict__ b9, float* __restrict__ vout)
{
    extern __shared__ float vals[];
    __shared__ int sidx[NP];
    __shared__ float wv[4];
    __shared__ int wi[4];
    __shared__ float ps[4];

    const int tid = threadIdx.x;
    const int b = blockIdx.x >> 5;
    const int k = blockIdx.x & 31;

    const float* src = y3 + ((size_t)b * 32 + k) * NPTS;
    const float sck = sc3[k], shk = sh3[k];
    for (int i = tid; i < NPTS; i += 256) vals[i] = fmaf(src[i], sck, shk);
    __syncthreads();

    for (int p = 0; p < NP; ++p) {
        float bv = INFINITY;
        int bi = 0x7fffffff;
        for (int i = tid; i < NPTS; i += 256) {
            float x = vals[i];
            if (x < bv) { bv = x; bi = i; }
        }
#pragma unroll
        for (int d = 32; d >= 1; d >>= 1) {
            float ov = __shfl_xor(bv, d, 64);
            int oi = __shfl_xor(bi, d, 64);
            if (ov < bv || (ov == bv && oi < bi)) { bv = ov; bi = oi; }
        }
        if ((tid & 63) == 0) { wv[tid >> 6] = bv; wi[tid >> 6] = bi; }
        __syncthreads();
        if (tid == 0) {
            for (int w = 1; w < 4; ++w)
                if (wv[w] < bv || (wv[w] == bv && wi[w] < bi)) { bv = wv[w]; bi = wi[w]; }
            sidx[p] = bi;
            vals[bi] = INFINITY;
        }
        __syncthreads();
    }

    float part = 0.f;
    for (int i = tid; i < 32 * NP; i += 256) {
        int c = i >> 4, p = i & 15;
        float h = fmaf(y3[((size_t)b * 32 + c) * NPTS + sidx[p]], sc3[c], sh3[c]);
        part += w9[c * NP + p] * h;
    }
#pragma unroll
    for (int d = 32; d >= 1; d >>= 1) part += __shfl_xor(part, d, 64);
    if ((tid & 63) == 0) ps[tid >> 6] = part;
    __syncthreads();
    if (tid == 0) vout[b * 32 + k] = ps[0] + ps[1] + ps[2] + ps[3] + b9[0];
}

// h1T[b][n][64] fp16 = relu(bn1(y1)), LDS transpose; S1b per-(b,c) sums.
__global__ __launch_bounds__(256) void transformT_k(
    const float* __restrict__ y1, const float* __restrict__ sc,
    const float* __restrict__ sh, f16* __restrict__ h1T, float* __restrict__ S1b)
{
    __shared__ float arr[64][65];
    __shared__ float s1loc[64];
    const int tid = threadIdx.x;
    const int b = blockIdx.x >> 8;
    const int n0 = (blockIdx.x & 255) * 64;
    if (tid < 64) s1loc[tid] = 0.f;

    const int c = tid >> 2, j4 = tid & 3;
    const float scv = sc[c], shv = sh[c];
    const float* src = y1 + ((size_t)b * 64 + c) * NPTS + n0 + j4 * 16;
    float ls = 0.f;
#pragma unroll
    for (int j = 0; j < 4; ++j) {
        float4 v = *(const float4*)(src + j * 4);
        float r0 = fmaxf(fmaf(v.x, scv, shv), 0.f);
        float r1 = fmaxf(fmaf(v.y, scv, shv), 0.f);
        float r2 = fmaxf(fmaf(v.z, scv, shv), 0.f);
        float r3 = fmaxf(fmaf(v.w, scv, shv), 0.f);
        arr[j4 * 16 + j * 4 + 0][c] = r0;
        arr[j4 * 16 + j * 4 + 1][c] = r1;
        arr[j4 * 16 + j * 4 + 2][c] = r2;
        arr[j4 * 16 + j * 4 + 3][c] = r3;
        ls += (r0 + r1) + (r2 + r3);
    }
    ls += __shfl_xor(ls, 1, 64);
    ls += __shfl_xor(ls, 2, 64);
    if (j4 == 0) atomicAdd(&s1loc[c], ls);
    __syncthreads();

    const int n = tid >> 2, cj = (tid & 3) * 16;
    f16x8 h0, h1v;
#pragma unroll
    for (int jj = 0; jj < 8; ++jj) h0[jj] = (f16)arr[n][cj + jj];
#pragma unroll
    for (int jj = 0; jj < 8; ++jj) h1v[jj] = (f16)arr[n][cj + 8 + jj];
    f16* dst = h1T + ((size_t)b * NPTS + n0 + n) * 64 + cj;
    *(f16x8*)(dst) = h0;
    *(f16x8*)(dst + 8) = h1v;

    if (tid < 64) atomicAdd(&S1b[b * 64 + tid], s1loc[tid]);
}

// ---------------------------------------------------------------------------
// MFMA SYRK: M[i][j] = sum_r H[r][i]*H[r][j], H = h1T [262144][64] fp16.
// For mfma_f32_16x16x32_f16, the A-frag (A[m][k]=H[k][m]) and B-frag
// (B[k][n]=H[k][n]) of lane l are the SAME data: H[k0+8*(l>>4)+i][l&15].
// So 4 frag loads (channel blocks) per 32 rows feed all 16 MFMAs of the
// 64x64 output. Exact fp16 products + fp32 accumulate (same math as the
// old VALU SYRK; only summation order differs -> post-pool-only 1e-7 shift).
// Grid: 512 blocks x 4 waves; 4 x 32-row steps per wave. Cross-wave reduce
// via 4 private LDS regions (no LDS atomics), then global atomicAdd.
// ---------------------------------------------------------------------------
__global__ __launch_bounds__(256, 2) void msyrk_k(const f16* __restrict__ h1T,
                                                  float* __restrict__ M)
{
    __shared__ float Mlds[4][4096];
    const int tid = threadIdx.x;
    const int lane = tid & 63;
    const int llo = lane & 15, lhi = lane >> 4;
    const int wv = tid >> 6;
    const int gw = blockIdx.x * 4 + wv;           // 2048 waves
    constexpr int SPW = (BNTOT / 32) / 2048;      // 4 steps/wave

    f32x4 acc[4][4];
#pragma unroll
    for (int ti = 0; ti < 4; ++ti)
#pragma unroll
        for (int tj = 0; tj < 4; ++tj) acc[ti][tj] = (f32x4){0.f, 0.f, 0.f, 0.f};

#pragma unroll
    for (int s = 0; s < SPW; ++s) {
        const size_t r0 = (size_t)gw * (SPW * 32) + (size_t)s * 32 + 8 * lhi;
        const f16* base = h1T + r0 * 64 + llo;
        f16x8 f[4];
#pragma unroll
        for (int t = 0; t < 4; ++t)
#pragma unroll
            for (int i = 0; i < 8; ++i)
                f[t][i] = base[(size_t)i * 64 + t * 16];
#pragma unroll
        for (int ti = 0; ti < 4; ++ti)
#pragma unroll
            for (int tj = 0; tj < 4; ++tj)
                acc[ti][tj] = __builtin_amdgcn_mfma_f32_16x16x32_f16(
                    f[ti], f[tj], acc[ti][tj], 0, 0, 0);
    }

    // D mapping (m89): row = ti*16 + 4*lhi + r, col = tj*16 + llo
#pragma unroll
    for (int ti = 0; ti < 4; ++ti)
#pragma unroll
        for (int tj = 0; tj < 4; ++tj)
#pragma unroll
            for (int r = 0; r < 4; ++r)
                Mlds[wv][(ti * 16 + 4 * lhi + r) * 64 + tj * 16 + llo] = acc[ti][tj][r];
    __syncthreads();
    for (int i = tid; i < 4096; i += 256)
        atomicAdd(&M[i], (Mlds[0][i] + Mlds[1][i]) + (Mlds[2][i] + Mlds[3][i]));
}

// BN4 from input moments; emits per-(b,o) fused shift.
__global__ void bnstats45_k(const float* __restrict__ w4, const float* __restrict__ vv,
                            const float* __restrict__ S1b, const float* __restrict__ M,
                            const float* __restrict__ g, const float* __restrict__ be,
                            float* __restrict__ sc4, float* __restrict__ shift4b)
{
    __shared__ float vvL[512], sbL[1024], ML[4096];
    const int tid = threadIdx.x;
    for (int i = tid; i < 512; i += 512) vvL[i] = vv[i];
    for (int i = tid; i < 1024; i += 512) sbL[i] = S1b[i];
    for (int i = tid; i < 4096; i += 512) ML[i] = M[i];
    __syncthreads();
    const int o = tid;
    float wg[32], wh[64];
#pragma unroll
    for (int i = 0; i < 32; ++i) wg[i] = w4[o * 96 + i];
#pragma unroll
    for (int j = 0; j < 64; ++j) wh[j] = w4[o * 96 + 32 + j];
    float gbv[16];
    float sumy = 0.f, sumsq = 0.f;
#pragma unroll
    for (int b = 0; b < 16; ++b) {
        float gb = 0.f, hb = 0.f;
#pragma unroll
        for (int i = 0; i < 32; ++i) gb = fmaf(wg[i], vvL[b * 32 + i], gb);
#pragma unroll
        for (int j = 0; j < 64; ++j) hb = fmaf(wh[j], sbL[b * 64 + j], hb);
        gbv[b] = gb;
        sumy += (float)NPTS * gb + hb;
        sumsq += (float)NPTS * gb * gb + 2.f * gb * hb;
    }
    for (int j = 0; j < 64; ++j) {
        float t = 0.f;
#pragma unroll
        for (int j2 = 0; j2 < 64; ++j2) t = fmaf(ML[j * 64 + j2], wh[j2], t);
        sumsq = fmaf(wh[j], t, sumsq);
    }
    const float inv = 1.0f / (float)BNTOT;
    float m = sumy * inv;
    float var = fmaf(sumsq, inv, -m * m);
    float s = g[o] / sqrtf(var + 1e-5f);
    float sh4v = fmaf(-m, s, be[o]);
    sc4[o] = s;
#pragma unroll
    for (int b = 0; b < 16; ++b)
        shift4b[b * 512 + o] = fmaf(gbv[b], s, sh4v);
}

// fp32 -> fp16 weight conversion (optionally a column slice of src)
__global__ void wcvt_k(const float* __restrict__ src, f16* __restrict__ dst,
                       int rows, int cols, int srcStride, int srcOff)
{
    int i = blockIdx.x * 256 + threadIdx.x;
    if (i < rows * cols) {
        int r = i / cols, c = i % cols;
        dst[i] = (f16)src[(size_t)r * srcStride + srcOff + c];
    }
}

// ---------------------------------------------------------------------------
// LDS-tiled MFMA GEMM (UNCHANGED from round 7).
// ---------------------------------------------------------------------------
#define GLOAD(KT, RA, RB)                                                       \
  {                                                                             \
    const int kb_ = (KT) * 64 + sj * 8;                                         \
    float4 is0, is1, ih0, ih1;                                                  \
    if (INAFF) {                                                                \
      is0 = *(const float4*)(insc + kb_); is1 = *(const float4*)(insc + kb_ + 4); \
      ih0 = *(const float4*)(insh + kb_); ih1 = *(const float4*)(insh + kb_ + 4); \
    }                                                                           \
    _Pragma("unroll")                                                           \
    for (int i_ = 0; i_ < 4; ++i_) {                                            \
      const int r_ = sr + i_ * 32;                                              \
      RA[i_] = *(const f16x8*)(wsrc + (size_t)r_ * K + kb_);                    \
      f16x8 xb = *(const f16x8*)(xsrc + (size_t)r_ * K + kb_);                  \
      if (INAFF) {                                                              \
        f16x8 nb;                                                               \
        nb[0] = (f16)fmaxf(fmaf((float)xb[0], is0.x, ih0.x), 0.f);              \
        nb[1] = (f16)fmaxf(fmaf((float)xb[1], is0.y, ih0.y), 0.f);              \
        nb[2] = (f16)fmaxf(fmaf((float)xb[2], is0.z, ih0.z), 0.f);              \
        nb[3] = (f16)fmaxf(fmaf((float)xb[3], is0.w, ih0.w), 0.f);              \
        nb[4] = (f16)fmaxf(fmaf((float)xb[4], is1.x, ih1.x), 0.f);              \
        nb[5] = (f16)fmaxf(fmaf((float)xb[5], is1.y, ih1.y), 0.f);              \
        nb[6] = (f16)fmaxf(fmaf((float)xb[6], is1.z, ih1.z), 0.f);              \
        nb[7] = (f16)fmaxf(fmaf((float)xb[7], is1.w, ih1.w), 0.f);              \
        xb = nb;                                                                \
      }                                                                         \
      RB[i_] = xb;                                                              \
    }                                                                           \
  }

#define DSWRITE(RA, RB)                                                         \
  {                                                                             \
    _Pragma("unroll")                                                           \
    for (int i_ = 0; i_ < 4; ++i_) {                                            \
      const int r_ = sr + i_ * 32;                                              \
      const int sw_ = sj ^ (r_ & 7);                                            \
      *(f16x8*)(&As[r_ * 64 + sw_ * 8]) = RA[i_];                               \
      *(f16x8*)(&Bs[r_ * 64 + sw_ * 8]) = RB[i_];                               \
    }                                                                           \
  }

template<int KS, bool INAFF, bool OUTAFF, bool STATS>
__global__ __launch_bounds__(256, 2) void gconv_k(
    const f16* __restrict__ Xt, const f16* __restrict__ Wh,
    const float* __restrict__ insc, const float* __restrict__ insh,
    const float* __restrict__ outsc, const float* __restrict__ outshB,
    f16* __restrict__ Y, float* __restrict__ ssum, float* __restrict__ ssq,
    const int M)
{
    constexpr int K = KS * 64;
    __shared__ __align__(16) f16 As[128 * 64];
    __shared__ __align__(16) f16 Bs[128 * 64];
    __shared__ float lsum[128];
    __shared__ float lsq[128];

    const int tid = threadIdx.x;
    const int w = tid >> 6, lane = tid & 63;
    const int llo = lane & 15, lhi = lane >> 4;
    const int wn = w >> 1, wm = w & 1;
    const int n0 = blockIdx.y * 128;
    const int m0 = blockIdx.x * 128;
    const int sr = tid >> 3, sj = tid & 7;

    if (STATS && tid < 128) { lsum[tid] = 0.f; lsq[tid] = 0.f; }

    const f16* xsrc = Xt + (size_t)n0 * K;
    const f16* wsrc = Wh + (size_t)m0 * K;

    f32x4 acc[4][4];
#pragma unroll
    for (int nf = 0; nf < 4; ++nf)
#pragma unroll
        for (int mf = 0; mf < 4; ++mf) acc[nf][mf] = (f32x4){0.f, 0.f, 0.f, 0.f};

    f16x8 ra0[4], rb0[4], ra1[4], rb1[4];
    GLOAD(0, ra0, rb0);

#pragma unroll
    for (int kt = 0; kt < KS; ++kt) {
        if ((kt & 1) == 0) { DSWRITE(ra0, rb0); } else { DSWRITE(ra1, rb1); }
        __syncthreads();
        if (kt + 1 < KS) {
            if ((kt & 1) == 0) { GLOAD(kt + 1, ra1, rb1); }
            else               { GLOAD(kt + 1, ra0, rb0); }
        }
#pragma unroll
        for (int ks = 0; ks < 2; ++ks) {
            f16x8 af[4], bf[4];
#pragma unroll
            for (int f = 0; f < 4; ++f) {
                const int ml = wm * 64 + f * 16 + llo;
                af[f] = *(const f16x8*)(&As[ml * 64 + ((ks * 4 + lhi) ^ (ml & 7)) * 8]);
                const int nl = wn * 64 + f * 16 + llo;
                bf[f] = *(const f16x8*)(&Bs[nl * 64 + ((ks * 4 + lhi) ^ (nl & 7)) * 8]);
            }
#pragma unroll
            for (int nf = 0; nf < 4; ++nf)
#pragma unroll
                for (int mf = 0; mf < 4; ++mf)
                    acc[nf][mf] = __builtin_amdgcn_mfma_f32_16x16x32_f16(
                        af[mf], bf[nf], acc[nf][mf], 0, 0, 0);
        }
        __syncthreads();
    }

    const int bl = n0 / NPTS;
#pragma unroll
    for (int nf = 0; nf < 4; ++nf) {
        const int n = n0 + wn * 64 + nf * 16 + llo;
        f16* row = Y + (size_t)n * M + m0 + wm * 64;
#pragma unroll
        for (int mf = 0; mf < 4; ++mf) {
            const int moff = mf * 16 + 4 * lhi;
            float v0 = acc[nf][mf][0], v1 = acc[nf][mf][1];
            float v2 = acc[nf][mf][2], v3 = acc[nf][mf][3];
            if (OUTAFF) {
                const int mg = m0 + wm * 64 + moff;
                float4 s = *(const float4*)(outsc + mg);
                float4 h = *(const float4*)(outshB + (size_t)bl * M + mg);
                v0 = fmaxf(fmaf(v0, s.x, h.x), 0.f);
                v1 = fmaxf(fmaf(v1, s.y, h.y), 0.f);
                v2 = fmaxf(fmaf(v2, s.z, h.z), 0.f);
                v3 = fmaxf(fmaf(v3, s.w, h.w), 0.f);
            }
            F16x4 o;
            o.v[0] = (f16)v0; o.v[1] = (f16)v1; o.v[2] = (f16)v2; o.v[3] = (f16)v3;
            *(F16x4*)(row + moff) = o;
        }
    }
    if (STATS) {
#pragma unroll
        for (int mf = 0; mf < 4; ++mf) {
#pragma unroll
            for (int r = 0; r < 4; ++r) {
                float s = acc[0][mf][r] + acc[1][mf][r] + acc[2][mf][r] + acc[3][mf][r];
                float q = fmaf(acc[0][mf][r], acc[0][mf][r],
                          fmaf(acc[1][mf][r], acc[1][mf][r],
                          fmaf(acc[2][mf][r], acc[2][mf][r],
                               acc[3][mf][r] * acc[3][mf][r])));
#pragma unroll
                for (int d = 1; d < 16; d <<= 1) {
                    s += __shfl_xor(s, d, 64);
                    q += __shfl_xor(q, d, 64);
                }
                if (llo == 0) {
                    atomicAdd(&lsum[wm * 64 + mf * 16 + 4 * lhi + r], s);
                    atomicAdd(&lsq [wm * 64 + mf * 16 + 4 * lhi + r], q);
                }
            }
        }
        __syncthreads();
        if (tid < 128) {
            atomicAdd(&ssum[m0 + tid], lsum[tid]);
            atomicAdd(&ssq [m0 + tid], lsq [tid]);
        }
    }
}

// conv7: out[b][o][n] = tanh(b7 + sum_c w7[o][c]*relu(bn6(y6T[n][c])))
__global__ __launch_bounds__(256) void conv7T_k(
    const f16* __restrict__ y6T, const float* __restrict__ sc6,
    const float* __restrict__ sh6, const float* __restrict__ w7,
    const float* __restrict__ b7, float* __restrict__ out)
{
    __shared__ float wsc[128], wsh[128], ww[384];
    const int tid = threadIdx.x;
    if (tid < 128) { wsc[tid] = sc6[tid]; wsh[tid] = sh6[tid]; }
    for (int i = tid; i < 384; i += 256) ww[i] = w7[i];
    __syncthreads();
    const int gid = blockIdx.x * 256 + tid;
    const int b = gid >> 14, nl = gid & 16383;
    const f16* row = y6T + (size_t)gid * 128;
    float a0 = 0.f, a1 = 0.f, a2 = 0.f;
    for (int c8 = 0; c8 < 128; c8 += 8) {
        f16x8 v8 = *(const f16x8*)(row + c8);
#pragma unroll
        for (int j = 0; j < 8; ++j) {
            float hv = fmaxf(fmaf((float)v8[j], wsc[c8 + j], wsh[c8 + j]), 0.f);
            a0 = fmaf(ww[c8 + j], hv, a0);
            a1 = fmaf(ww[128 + c8 + j], hv, a1);
            a2 = fmaf(ww[256 + c8 + j], hv, a2);
        }
    }
    const float bv = b7[0];
    out[((size_t)b * 3 + 0) * NPTS + nl] = tanhf(a0 + bv);
    out[((size_t)b * 3 + 1) * NPTS + nl] = tanhf(a1 + bv);
    out[((size_t)b * 3 + 2) * NPTS + nl] = tanhf(a2 + bv);
}

// Diagnostic fallback
__global__ void fill_k(float* __restrict__ out, int nsize, float val)
{
    int i = blockIdx.x * 256 + threadIdx.x;
    if (i < nsize) out[i] = val;
}

extern "C" void kernel_launch(void* const* d_in, const int* in_sizes, int n_in,
                              void* d_out, int out_size, void* d_ws, size_t ws_size,
                              hipStream_t stream)
{
    const float* x   = (const float*)d_in[0];
    const float* w1  = (const float*)d_in[1];
    const float* g1  = (const float*)d_in[3];
    const float* be1 = (const float*)d_in[4];
    const float* w2  = (const float*)d_in[5];
    const float* g2  = (const float*)d_in[7];
    const float* be2 = (const float*)d_in[8];
    const float* w3  = (const float*)d_in[9];
    const float* g3  = (const float*)d_in[11];
    const float* be3 = (const float*)d_in[12];
    const float* w9  = (const float*)d_in[13];
    const float* b9  = (const float*)d_in[14];
    const float* w4  = (const float*)d_in[15];
    const float* g4  = (const float*)d_in[17];
    const float* be4 = (const float*)d_in[18];
    const float* w5  = (const float*)d_in[19];
    const float* g5  = (const float*)d_in[21];
    const float* be5 = (const float*)d_in[22];
    const float* w6  = (const float*)d_in[23];
    const float* g6  = (const float*)d_in[25];
    const float* be6 = (const float*)d_in[26];
    const float* w7  = (const float*)d_in[27];
    const float* b7  = (const float*)d_in[28];
    float* out = (float*)d_out;

    // ---- workspace plan (226 MiB), lifetime-aliased (unchanged) ----
    const size_t MB = 1048576u;
    const size_t need = 226 * MB;
    if (ws_size < need) {
        float val = 1000.0f + (float)(ws_size >> 20);
        fill_k<<<(out_size + 255) / 256, 256, 0, stream>>>(out, out_size, val);
        return;
    }

    char* base = (char*)d_ws;
    float* y1  = (float*)(base + 1 * MB);
    f16*   y4T = (f16*)(base + 1 * MB);
    f16*   y6T = (f16*)(base + 1 * MB);
    float* y2  = (float*)(base + 65 * MB);
    f16*   h1T = (f16*)(base + 65 * MB);
    f16*   y5T = (f16*)(base + 97 * MB);
    float* y3  = (float*)(base + 193 * MB);
    float* sm  = (float*)(base + 225 * MB);
    f16*   w5h = (f16*)(base + 225 * MB + 131072);
    f16*   w6h = w5h + 131072;   // 256*512
    f16*   w4hh = w6h + 32768;   // 128*256; w4hh is 512*64

    float* sum1 = sm + 0,     *sq1 = sm + 512,  *sc1 = sm + 1024, *sh1 = sm + 1536;
    float* sum2 = sm + 2048,  *sq2 = sm + 2560, *sc2 = sm + 3072, *sh2 = sm + 3584;
    float* sum3 = sm + 4096,  *sq3 = sm + 4608, *sc3 = sm + 5120, *sh3 = sm + 5632;
    float* sc4  = sm + 6144;
    float* sum5 = sm + 7168,  *sq5 = sm + 7680, *sc5 = sm + 8192, *sh5 = sm + 8704;
    float* sum6 = sm + 9216,  *sq6 = sm + 9728, *sc6 = sm + 10240,*sh6 = sm + 10752;
    float* vv   = sm + 11264;            // 512
    float* S1b  = sm + 11776;            // 1024
    float* Mh   = sm + 12800;            // 4096
    float* shift4b = sm + 16896;         // 16*512 -> end 25088

    hipMemsetAsync(sm, 0, 16896 * sizeof(float), stream);

    const dim3 blk(256);
    const int tilesF = BNTOT / 1024;     // 256

    // fp16 weight copies
    wcvt_k<<<(256 * 512 + 255) / 256, blk, 0, stream>>>(w5, w5h, 256, 512, 512, 0);
    wcvt_k<<<(128 * 256 + 255) / 256, blk, 0, stream>>>(w6, w6h, 128, 256, 256, 0);
    wcvt_k<<<(512 * 64 + 255) / 256, blk, 0, stream>>>(w4, w4hh, 512, 64, 96, 32);

    // conv1..conv3 (fp32, bit-identical)
    conv_k<4, 32, 0, false, true, false, float, float>
        <<<dim3(2, tilesF), blk, 0, stream>>>(x, nullptr, w1, nullptr, nullptr, nullptr,
            nullptr, nullptr, y1, sum1, sq1, 64);
    bnstats_k<<<1, 256, 0, stream>>>(sum1, sq1, g1, be1, sc1, sh1, 64);

    conv_k<64, 32, 1, false, true, false, float, float>
        <<<dim3(4, tilesF), blk, 0, stream>>>(y1, nullptr, w2, nullptr, sc1, sh1,
            nullptr, nullptr, y2, sum2, sq2, 128);
    bnstats_k<<<1, 256, 0, stream>>>(sum2, sq2, g2, be2, sc2, sh2, 128);

    conv_k<128, 32, 1, false, true, false, float, float>
        <<<dim3(1, tilesF), blk, 0, stream>>>(y2, nullptr, w3, nullptr, sc2, sh2,
            nullptr, nullptr, y3, sum3, sq3, 32);
    bnstats_k<<<1, 256, 0, stream>>>(sum3, sq3, g3, be3, sc3, sh3, 32);

    softpool_k<<<512, blk, NPTS * sizeof(float), stream>>>(y3, sc3, sh3, w9, b9, vv);

    // h1T + S1b, MFMA SYRK moment, BN4 (fused per-(b,o) shift)
    transformT_k<<<16 * 256, blk, 0, stream>>>(y1, sc1, sh1, h1T, S1b);
    msyrk_k<<<512, blk, 0, stream>>>(h1T, Mh);
    bnstats45_k<<<1, 512, 0, stream>>>(w4, vv, S1b, Mh, g4, be4, sc4, shift4b);

    // conv4+conv5 in 4 batch-chunks (tiled MFMA GEMM); y4T bounce in y1 region
    for (int q = 0; q < 4; ++q) {
        const f16* h1q = h1T + (size_t)q * 4 * NPTS * 64;
        f16* y5q = y5T + (size_t)q * 4 * NPTS * 256;
        // conv4: K=64 -> M=512, OUTAFF(sc4, shift4b per-b)
        gconv_k<1, false, true, false><<<dim3(4, 512), blk, 0, stream>>>(
            h1q, w4hh, nullptr, nullptr, sc4, shift4b + (size_t)q * 4 * 512,
            y4T, nullptr, nullptr, 512);
        // conv5: K=512 -> M=256, raw + stats
        gconv_k<8, false, false, true><<<dim3(2, 512), blk, 0, stream>>>(
            y4T, w5h, nullptr, nullptr, nullptr, nullptr,
            y5q, sum5, sq5, 256);
    }
    bnstats_k<<<1, 256, 0, stream>>>(sum5, sq5, g5, be5, sc5, sh5, 256);

    // conv6: K=256 -> M=128, INAFF(bn5+relu at staging), raw + stats
    gconv_k<4, true, false, true><<<dim3(1, 2048), blk, 0, stream>>>(
        y5T, w6h, sc5, sh5, nullptr, nullptr,
        y6T, sum6, sq6, 128);
    bnstats_k<<<1, 256, 0, stream>>>(sum6, sq6, g6, be6, sc6, sh6, 128);

    // conv7: VALU, bn6+relu on load, tanh out
    conv7T_k<<<BNTOT / 256, blk, 0, stream>>>(y6T, sc6, sh6, w7, b7, out);
}